// Round 3
// baseline (2717.815 us; speedup 1.0000x reference)
//
#include <hip/hip_runtime.h>
#include <stdint.h>

// ---------------- helpers ----------------
__device__ __forceinline__ float relu_(float v){ return v > 0.f ? v : 0.f; }

// order-preserving float->uint encoding for atomicMax (0 encodes < any finite)
__device__ __forceinline__ unsigned encf(float f){
  unsigned u = __float_as_uint(f);
  return (u & 0x80000000u) ? ~u : (u | 0x80000000u);
}
__device__ __forceinline__ float decf(unsigned e){
  return (e & 0x80000000u) ? __uint_as_float(e ^ 0x80000000u) : __uint_as_float(~e);
}

// ---------------- layouts ----------------
// STD (f64): 4 BN regions x [8 slices][2][256]  (sum at +0..255, sqs at +256..511 per slice)
//   region stride 4096 doubles. BN idx: 0=input, 1=mlp(256col), 2=n0, 3=n1
// STF (f32): 4 BN regions x 512 floats: a at base+0..255, b at base+256..511
//   bases: in=0, mlp=512, n0=1024, n1=1536

#define STD_BN(p, idx) ((p) + (size_t)(idx) * 4096)

// ---- input projection: L0(f32) = x@W_in + b_in (pre-BN), + f64 col stats ----
__global__ __launch_bounds__(128) void k_inproj(
    const float* __restrict__ x, const float* __restrict__ W_in,
    const float* __restrict__ b_in, float* __restrict__ y0,
    double* __restrict__ STD0, int N)
{
  const int d = threadIdx.x;
  float w[10];
  #pragma unroll
  for (int k = 0; k < 10; ++k) w[k] = W_in[k*128 + d];
  const float bi = b_in[d];
  int r0 = blockIdx.x * 128;
  int rend = min(r0 + 128, N);
  double sum = 0.0, sqs = 0.0;
  for (int r = r0; r < rend; ++r) {
    const float* xr = x + (size_t)r * 10;
    float acc = bi;
    #pragma unroll
    for (int k = 0; k < 10; ++k) acc += xr[k] * w[k];
    y0[(size_t)r*128 + d] = acc;
    double a = (double)acc;
    sum += a; sqs += a*a;
  }
  int slice = blockIdx.x & 7;
  atomicAdd(&STD0[slice*512 + d], sum);
  atomicAdd(&STD0[slice*512 + 256 + d], sqs);
}

// ---- BN finalize: a = g*rsqrt(var+eps), b = beta - mean*a (f64 math) ----
__global__ void k_bnfin(const double* __restrict__ STDbn,
                        const float* __restrict__ g, const float* __restrict__ beta,
                        float* __restrict__ STFbn, int colofs, double invN)
{
  int col = colofs + threadIdx.x;
  double s = 0.0, q = 0.0;
  #pragma unroll
  for (int sl = 0; sl < 8; ++sl) {
    s += STDbn[sl*512 + col];
    q += STDbn[sl*512 + 256 + col];
  }
  double m = s * invN;
  double var = q * invN - m*m;
  double av = (double)g[col] / sqrt(var + 1e-5);
  STFbn[col] = (float)av;
  STFbn[256 + col] = (float)((double)beta[col] - m*av);
}

// ---- in-place affine + relu on f32 [N,128] (float4) ----
__global__ __launch_bounds__(256) void k_affrelu(float* __restrict__ buf,
    const float* __restrict__ STF0, long total4)
{
  long g = (long)blockIdx.x*256 + threadIdx.x;
  if (g >= total4) return;
  int d0 = (int)((g*4) & 127);
  float4 v = ((const float4*)buf)[g];
  float4 av = *(const float4*)(STF0 + d0);
  float4 bv = *(const float4*)(STF0 + 256 + d0);
  v.x = relu_(av.x*v.x + bv.x);
  v.y = relu_(av.y*v.y + bv.y);
  v.z = relu_(av.z*v.z + bv.z);
  v.w = relu_(av.w*v.w + bv.w);
  ((float4*)buf)[g] = v;
}

// ---- GINE edge: agg[dst] += relu(l0[src] + eattr@We + be) ----
__global__ __launch_bounds__(256) void k_gine_edge(
  const int* __restrict__ src, const int* __restrict__ dst,
  const float* __restrict__ eattr, const float* __restrict__ We,
  const float* __restrict__ be, const float* __restrict__ l0,
  float* __restrict__ agg, long total)
{
  long g = (long)blockIdx.x*256 + threadIdx.x;
  if (g >= total) return;
  int e = (int)(g >> 7);
  int d = (int)(g & 127);
  int s = src[e], t = dst[e];
  float ep = be[d];
  #pragma unroll
  for (int i = 0; i < 5; ++i) ep += eattr[(size_t)e*5 + i] * We[i*128 + d];
  float m = relu_(l0[(size_t)s*128 + d] + ep);
  atomicAdd(&agg[(size_t)t*128 + d], m);
}

// ---- GEMM1 (one col-half): y1h[N,128] = (l0+agg) @ W1[:,colofs:colofs+128] + b1, + f64 stats ----
__global__ __launch_bounds__(256) void k_gemm_gine1(
  const float* __restrict__ l0, const float* __restrict__ agg,
  const float* __restrict__ W1, const float* __restrict__ b1,
  float* __restrict__ y1h, double* __restrict__ STD1, int colofs, int N)
{
  __shared__ float As[64][68];
  __shared__ double reds[16][64];
  __shared__ double redq[16][64];
  const int tid = threadIdx.x;
  const int tx = tid & 15, ty = tid >> 4;
  const int row0 = blockIdx.x * 64;
  const int ct = blockIdx.y * 64;          // 0 or 64 within the half
  const int ar = tid >> 2, ac = tid & 3;
  float acc[4][4] = {};
  for (int kb = 0; kb < 128; kb += 64) {
    int r = row0 + ar;
    #pragma unroll
    for (int jj = 0; jj < 4; ++jj) {
      int kl = ac*16 + jj*4;
      float4 v = make_float4(0.f,0.f,0.f,0.f);
      if (r < N) {
        float4 a4 = *(const float4*)(l0  + (size_t)r*128 + kb + kl);
        float4 g4 = *(const float4*)(agg + (size_t)r*128 + kb + kl);
        v.x=a4.x+g4.x; v.y=a4.y+g4.y; v.z=a4.z+g4.z; v.w=a4.w+g4.w;
      }
      As[kl+0][ar]=v.x; As[kl+1][ar]=v.y; As[kl+2][ar]=v.z; As[kl+3][ar]=v.w;
    }
    __syncthreads();
    #pragma unroll 8
    for (int k = 0; k < 64; ++k) {
      float4 a = *(const float4*)&As[k][ty*4];
      float4 b = *(const float4*)(W1 + (size_t)(kb+k)*256 + colofs + ct + tx*4);
      float av[4]={a.x,a.y,a.z,a.w}, bv[4]={b.x,b.y,b.z,b.w};
      #pragma unroll
      for (int i=0;i<4;++i)
        #pragma unroll
        for (int j=0;j<4;++j) acc[i][j] += av[i]*bv[j];
    }
    __syncthreads();
  }
  float4 bb = *(const float4*)(b1 + colofs + ct + tx*4);
  float bvv[4] = {bb.x,bb.y,bb.z,bb.w};
  double s[4] = {0.0,0.0,0.0,0.0}, q[4] = {0.0,0.0,0.0,0.0};
  #pragma unroll
  for (int i = 0; i < 4; ++i) {
    int r = row0 + ty*4 + i;
    if (r < N) {
      float4 o;
      o.x=acc[i][0]+bvv[0]; o.y=acc[i][1]+bvv[1];
      o.z=acc[i][2]+bvv[2]; o.w=acc[i][3]+bvv[3];
      *(float4*)(y1h + (size_t)r*128 + ct + tx*4) = o;
      double vv[4] = {o.x,o.y,o.z,o.w};
      #pragma unroll
      for (int j=0;j<4;++j){ s[j] += vv[j]; q[j] += vv[j]*vv[j]; }
    }
  }
  #pragma unroll
  for (int j=0;j<4;++j){ reds[ty][tx*4+j] = s[j]; redq[ty][tx*4+j] = q[j]; }
  __syncthreads();
  if (tid < 64) {
    double ss=0.0, qq=0.0;
    #pragma unroll
    for (int t2=0; t2<16; ++t2){ ss += reds[t2][tid]; qq += redq[t2][tid]; }
    int col = colofs + ct + tid;
    int slice = blockIdx.x & 7;
    atomicAdd(&STD1[slice*512 + col], ss);
    atomicAdd(&STD1[slice*512 + 256 + col], qq);
  }
}

// ---- GEMM2a: P1 = relu(a1*y1h+c1) @ W2[0:128,:]  (raw partial, no bias) ----
__global__ __launch_bounds__(256) void k_gemm_gine2a(
  const float* __restrict__ y1h, const float* __restrict__ STF,
  const float* __restrict__ W2, float* __restrict__ P1, int N, int kofs)
{
  __shared__ float As[64][68];
  const int tid = threadIdx.x;
  const int tx = tid & 15, ty = tid >> 4;
  const int row0 = blockIdx.x * 64;
  const int ct = blockIdx.y * 64;
  const int ar = tid >> 2, ac = tid & 3;
  float acc[4][4] = {};
  for (int kb = 0; kb < 128; kb += 64) {
    int r = row0 + ar;
    #pragma unroll
    for (int jj = 0; jj < 4; ++jj) {
      int kl = ac*16 + jj*4;
      float4 v = make_float4(0.f,0.f,0.f,0.f);
      if (r < N) {
        float4 t4 = *(const float4*)(y1h + (size_t)r*128 + kb + kl);
        float4 a1 = *(const float4*)(STF + 512 + kofs + kb + kl);
        float4 c1 = *(const float4*)(STF + 768 + kofs + kb + kl);
        v.x = relu_(a1.x*t4.x + c1.x);
        v.y = relu_(a1.y*t4.y + c1.y);
        v.z = relu_(a1.z*t4.z + c1.z);
        v.w = relu_(a1.w*t4.w + c1.w);
      }
      As[kl+0][ar]=v.x; As[kl+1][ar]=v.y; As[kl+2][ar]=v.z; As[kl+3][ar]=v.w;
    }
    __syncthreads();
    #pragma unroll 8
    for (int k = 0; k < 64; ++k) {
      float4 a = *(const float4*)&As[k][ty*4];
      float4 b = *(const float4*)(W2 + (size_t)(kofs+kb+k)*128 + ct + tx*4);
      float av[4]={a.x,a.y,a.z,a.w}, bv[4]={b.x,b.y,b.z,b.w};
      #pragma unroll
      for (int i=0;i<4;++i)
        #pragma unroll
        for (int j=0;j<4;++j) acc[i][j] += av[i]*bv[j];
    }
    __syncthreads();
  }
  #pragma unroll
  for (int i = 0; i < 4; ++i) {
    int r = row0 + ty*4 + i;
    if (r < N) {
      float4 o; o.x=acc[i][0]; o.y=acc[i][1]; o.z=acc[i][2]; o.w=acc[i][3];
      *(float4*)(P1 + (size_t)r*128 + ct + tx*4) = o;
    }
  }
}

// ---- GEMM2b: tot = P1 + relu(a1*y1h+c1)@W2[128:256,:] + b2;
//      pre1 = s0*l0 + (1-s0)*relu(tot); store P1; + f64 stats (BN n0) ----
__global__ __launch_bounds__(256) void k_gemm_gine2b(
  const float* __restrict__ y1h, const float* __restrict__ STF,
  const float* __restrict__ W2, const float* __restrict__ b2,
  const float* __restrict__ l0, const float* __restrict__ skip0,
  float* __restrict__ P1, double* __restrict__ STD2, int N, int kofs)
{
  __shared__ float As[64][68];
  __shared__ double reds[16][64];
  __shared__ double redq[16][64];
  const int tid = threadIdx.x;
  const int tx = tid & 15, ty = tid >> 4;
  const int row0 = blockIdx.x * 64;
  const int ct = blockIdx.y * 64;
  const int ar = tid >> 2, ac = tid & 3;
  float acc[4][4] = {};
  for (int kb = 0; kb < 128; kb += 64) {
    int r = row0 + ar;
    #pragma unroll
    for (int jj = 0; jj < 4; ++jj) {
      int kl = ac*16 + jj*4;
      float4 v = make_float4(0.f,0.f,0.f,0.f);
      if (r < N) {
        float4 t4 = *(const float4*)(y1h + (size_t)r*128 + kb + kl);
        float4 a1 = *(const float4*)(STF + 512 + kofs + kb + kl);
        float4 c1 = *(const float4*)(STF + 768 + kofs + kb + kl);
        v.x = relu_(a1.x*t4.x + c1.x);
        v.y = relu_(a1.y*t4.y + c1.y);
        v.z = relu_(a1.z*t4.z + c1.z);
        v.w = relu_(a1.w*t4.w + c1.w);
      }
      As[kl+0][ar]=v.x; As[kl+1][ar]=v.y; As[kl+2][ar]=v.z; As[kl+3][ar]=v.w;
    }
    __syncthreads();
    #pragma unroll 8
    for (int k = 0; k < 64; ++k) {
      float4 a = *(const float4*)&As[k][ty*4];
      float4 b = *(const float4*)(W2 + (size_t)(kofs+kb+k)*128 + ct + tx*4);
      float av[4]={a.x,a.y,a.z,a.w}, bv[4]={b.x,b.y,b.z,b.w};
      #pragma unroll
      for (int i=0;i<4;++i)
        #pragma unroll
        for (int j=0;j<4;++j) acc[i][j] += av[i]*bv[j];
    }
    __syncthreads();
  }
  float s0g = 1.f/(1.f + expf(-skip0[0]));
  float os0 = 1.f - s0g;
  float4 bb = *(const float4*)(b2 + ct + tx*4);
  float bvv[4] = {bb.x,bb.y,bb.z,bb.w};
  double s[4] = {0.0,0.0,0.0,0.0}, q[4] = {0.0,0.0,0.0,0.0};
  #pragma unroll
  for (int i = 0; i < 4; ++i) {
    int r = row0 + ty*4 + i;
    if (r < N) {
      size_t base = (size_t)r*128 + ct + tx*4;
      float4 prev = *(const float4*)(P1 + base);
      float4 l4 = *(const float4*)(l0 + base);
      float pv[4] = {prev.x,prev.y,prev.z,prev.w};
      float lv[4] = {l4.x,l4.y,l4.z,l4.w};
      float4 o; float* op = (float*)&o;
      #pragma unroll
      for (int j=0;j<4;++j) {
        float tot = pv[j] + acc[i][j] + bvv[j];
        float pre1 = s0g*lv[j] + os0*relu_(tot);
        op[j] = pre1;
        double dv = (double)pre1;
        s[j] += dv; q[j] += dv*dv;
      }
      *(float4*)(P1 + base) = o;
    }
  }
  #pragma unroll
  for (int j=0;j<4;++j){ reds[ty][tx*4+j] = s[j]; redq[ty][tx*4+j] = q[j]; }
  __syncthreads();
  if (tid < 64) {
    double ss=0.0, qq=0.0;
    #pragma unroll
    for (int t2=0; t2<16; ++t2){ ss += reds[t2][tid]; qq += redq[t2][tid]; }
    int col = ct + tid;
    int slice = blockIdx.x & 7;
    atomicAdd(&STD2[slice*512 + col], ss);
    atomicAdd(&STD2[slice*512 + 256 + col], qq);
  }
}

// ---- GAT transform: out[N,ow] = (an0*P1+bn0) @ W[:, cb..cb+ow) + bias ----
__global__ __launch_bounds__(256) void k_gemm_gat(
  const float* __restrict__ P1, const float* __restrict__ STF,
  const float* __restrict__ W, const float* __restrict__ bias,
  float* __restrict__ outp, int N, int cb, int ow, int ob)
{
  __shared__ float As[64][68];
  const int tid = threadIdx.x;
  const int tx = tid & 15, ty = tid >> 4;
  const int row0 = blockIdx.x * 64;
  const int ar = tid >> 2, ac = tid & 3;
  float acc[4][4] = {};
  for (int kb = 0; kb < 128; kb += 64) {
    int r = row0 + ar;
    #pragma unroll
    for (int jj = 0; jj < 4; ++jj) {
      int kl = ac*16 + jj*4;
      int k = kb + kl;
      float4 v = make_float4(0.f,0.f,0.f,0.f);
      if (r < N) {
        float4 t4 = *(const float4*)(P1 + (size_t)r*128 + k);
        float4 an = *(const float4*)(STF + 1024 + k);
        float4 bn = *(const float4*)(STF + 1280 + k);
        v.x = an.x*t4.x + bn.x;
        v.y = an.y*t4.y + bn.y;
        v.z = an.z*t4.z + bn.z;
        v.w = an.w*t4.w + bn.w;
      }
      As[kl+0][ar]=v.x; As[kl+1][ar]=v.y; As[kl+2][ar]=v.z; As[kl+3][ar]=v.w;
    }
    __syncthreads();
    #pragma unroll 8
    for (int k = 0; k < 64; ++k) {
      float4 a = *(const float4*)&As[k][ty*4];
      float4 b = *(const float4*)(W + (size_t)(kb+k)*512 + cb + tx*4);
      float av[4]={a.x,a.y,a.z,a.w}, bv[4]={b.x,b.y,b.z,b.w};
      #pragma unroll
      for (int i=0;i<4;++i)
        #pragma unroll
        for (int j=0;j<4;++j) acc[i][j] += av[i]*bv[j];
    }
    __syncthreads();
  }
  float4 bb = *(const float4*)(bias + cb + tx*4);
  float bvv[4] = {bb.x,bb.y,bb.z,bb.w};
  #pragma unroll
  for (int i = 0; i < 4; ++i) {
    int r = row0 + ty*4 + i;
    if (r < N) {
      float4 o;
      o.x=acc[i][0]+bvv[0]; o.y=acc[i][1]+bvv[1];
      o.z=acc[i][2]+bvv[2]; o.w=acc[i][3]+bvv[3];
      *(float4*)(outp + (size_t)r*ow + ob + tx*4) = o;
    }
  }
}

// ---- GAT partial logits for one head, one 64-wide d-half; wave per edge ----
__global__ __launch_bounds__(256) void k_gat_logit_half(
  const int* __restrict__ src, const int* __restrict__ dst,
  const float* __restrict__ eattr, const float* __restrict__ xl,
  const float* __restrict__ xrh, const float* __restrict__ Weg,
  const float* __restrict__ att, float* __restrict__ LG,
  unsigned* __restrict__ MX, int E, int h, int dh)
{
  int wave = threadIdx.x >> 6;
  int lane = threadIdx.x & 63;
  int e = blockIdx.x*4 + wave;
  if (e >= E) return;
  int s = src[e], t = dst[e];
  float ea[5];
  #pragma unroll
  for (int i = 0; i < 5; ++i) ea[i] = eattr[(size_t)e*5 + i];
  int dcol = h*128 + dh*64 + lane;
  float f = xl[(size_t)s*128 + dh*64 + lane] + xrh[(size_t)t*64 + lane];
  #pragma unroll
  for (int i = 0; i < 5; ++i) f += ea[i] * Weg[i*512 + dcol];
  f = f > 0.f ? f : 0.2f*f;
  float p = f * att[dcol];
  #pragma unroll
  for (int m = 1; m < 64; m <<= 1) p += __shfl_xor(p, m, 64);
  if (lane == 0) {
    if (dh == 0) {
      LG[e] = p;
    } else {
      float tot = LG[e] + p;
      LG[e] = tot;
      atomicMax(&MX[t], encf(tot));
    }
  }
}

// ---- exp + denominator (one head) ----
__global__ __launch_bounds__(256) void k_gat_expdenh(
  const int* __restrict__ dst, float* __restrict__ LG,
  const unsigned* __restrict__ MX, float* __restrict__ DN, int E)
{
  int e = blockIdx.x*256 + threadIdx.x;
  if (e >= E) return;
  int t = dst[e];
  float ex = expf(LG[e] - decf(MX[t]));
  LG[e] = ex;
  atomicAdd(&DN[t], ex);
}

// ---- weighted scatter (one head): AG[dst] += 0.25*alpha*xl[src]; wave per edge ----
__global__ __launch_bounds__(256) void k_gat_scath(
  const int* __restrict__ src, const int* __restrict__ dst,
  const float* __restrict__ LG, const float* __restrict__ DN,
  const float* __restrict__ xl, float* __restrict__ AG, int E)
{
  int wave = threadIdx.x >> 6;
  int lane = threadIdx.x & 63;
  int e = blockIdx.x*4 + wave;
  if (e >= E) return;
  int s = src[e], t = dst[e];
  float al = 0.25f * LG[e] / DN[t];
  float2 v = *(const float2*)(xl + (size_t)s*128 + 2*lane);
  atomicAdd(&AG[(size_t)t*128 + 2*lane + 0], al*v.x);
  atomicAdd(&AG[(size_t)t*128 + 2*lane + 1], al*v.y);
}

// ---- GAT post: pre2 = s1*(an0*P1+bn0) + (1-s1)*relu(AG+bias); in-place AG; + f64 stats ----
__global__ __launch_bounds__(128) void k_gat_post(
  float* __restrict__ AG, const float* __restrict__ P1,
  const float* __restrict__ STF, const float* __restrict__ bias_gat,
  const float* __restrict__ skip1, double* __restrict__ STD3, int N)
{
  int d = threadIdx.x;
  float an0 = STF[1024 + d], bn0 = STF[1280 + d];
  float bg = bias_gat[d];
  float s1g = 1.f/(1.f + expf(-skip1[0]));
  float os1 = 1.f - s1g;
  int r0 = blockIdx.x * 256;
  int rend = min(r0 + 256, N);
  double sum = 0.0, sqs = 0.0;
  for (int r = r0; r < rend; ++r) {
    size_t idx = (size_t)r*128 + d;
    float xn = relu_(AG[idx] + bg);
    float l1 = an0*P1[idx] + bn0;
    float p2 = s1g*l1 + os1*xn;
    AG[idx] = p2;
    double dv = (double)p2;
    sum += dv; sqs += dv*dv;
  }
  int slice = blockIdx.x & 7;
  atomicAdd(&STD3[slice*512 + d], sum);
  atomicAdd(&STD3[slice*512 + 256 + d], sqs);
}

// ---- final: d_out(f32, in-place over L0) = (L0 + (an0*P1+bn0) + (an1*pre2+bn1)) / 3 ----
__global__ __launch_bounds__(256) void k_final(
  float* __restrict__ L0, const float* __restrict__ P1,
  const float* __restrict__ pre2, const float* __restrict__ STF, long total4)
{
  long g = (long)blockIdx.x*256 + threadIdx.x;
  if (g >= total4) return;
  int d0 = (int)((g*4) & 127);
  float4 a0 = *(const float4*)(STF + 1024 + d0);
  float4 b0 = *(const float4*)(STF + 1280 + d0);
  float4 a1 = *(const float4*)(STF + 1536 + d0);
  float4 b1 = *(const float4*)(STF + 1792 + d0);
  float4 v0 = ((const float4*)L0)[g];
  float4 v1 = ((const float4*)P1)[g];
  float4 v2 = ((const float4*)pre2)[g];
  float4 o;
  const float k3 = 1.f/3.f;
  o.x = (v0.x + (a0.x*v1.x + b0.x) + (a1.x*v2.x + b1.x)) * k3;
  o.y = (v0.y + (a0.y*v1.y + b0.y) + (a1.y*v2.y + b1.y)) * k3;
  o.z = (v0.z + (a0.z*v1.z + b0.z) + (a1.z*v2.z + b1.z)) * k3;
  o.w = (v0.w + (a0.w*v1.w + b0.w) + (a1.w*v2.w + b1.w)) * k3;
  ((float4*)L0)[g] = o;
}

// ---------------- host launch ----------------
extern "C" void kernel_launch(void* const* d_in, const int* in_sizes, int n_in,
                              void* d_out, int out_size, void* d_ws, size_t ws_size,
                              hipStream_t stream)
{
  const float* x       = (const float*)d_in[0];
  const int*   eidx    = (const int*)  d_in[1];
  const float* eattr   = (const float*)d_in[2];
  const float* W_in    = (const float*)d_in[4];
  const float* b_in    = (const float*)d_in[5];
  const float* g_in    = (const float*)d_in[6];
  const float* beta_in = (const float*)d_in[7];
  const float* We      = (const float*)d_in[8];
  const float* be      = (const float*)d_in[9];
  const float* W1      = (const float*)d_in[10];
  const float* b1      = (const float*)d_in[11];
  const float* g1      = (const float*)d_in[12];
  const float* beta1   = (const float*)d_in[13];
  const float* W2      = (const float*)d_in[14];
  const float* b2      = (const float*)d_in[15];
  const float* skip0   = (const float*)d_in[16];
  const float* skip1   = (const float*)d_in[17];
  const float* g_n0    = (const float*)d_in[18];
  const float* b_n0    = (const float*)d_in[19];
  const float* g_n1    = (const float*)d_in[20];
  const float* b_n1    = (const float*)d_in[21];
  const float* Wl      = (const float*)d_in[22];
  const float* bl      = (const float*)d_in[23];
  const float* Wr      = (const float*)d_in[24];
  const float* br      = (const float*)d_in[25];
  const float* att     = (const float*)d_in[26];
  const float* Weg     = (const float*)d_in[27];
  const float* bias_g  = (const float*)d_in[28];

  const int N = in_sizes[0] / 10;
  const int E = in_sizes[1] / 2;
  const int* srcv = eidx;
  const int* dstv = eidx + E;

  // L0 (layer0, f32 [N,128]) lives in d_out; finalized in place.
  float* L0 = (float*)d_out;

  // ---- workspace layout (~181 MB) ----
  char* wsb = (char*)d_ws;
  const size_t szN128 = (size_t)N*128*4;
  size_t oAG  = 0;                        // f32 [N,128]: gine agg -> GAT accum -> pre2
  size_t oP1  = oAG + szN128;             // f32 [N,128]: gemm2a partial -> pre1
  size_t oR2  = oP1 + szN128;             // region: y1h [N,128] f32; later XL/XRh/LG/MX/DN
  size_t oSTD = oR2 + szN128 + (size_t)N*64*4 + (size_t)E*4 + (size_t)N*4*2;
  size_t oSTF = oSTD + 16384*8;

  float*    AG  = (float*)(wsb + oAG);
  float*    P1  = (float*)(wsb + oP1);
  float*    Y1h = (float*)(wsb + oR2);                        // [N,128] (gemm phase)
  float*    XL  = (float*)(wsb + oR2);                        // [N,128] (GAT phase)
  float*    XRh = (float*)(wsb + oR2 + szN128);               // [N,64]
  float*    LG  = (float*)(wsb + oR2 + szN128 + (size_t)N*64*4);
  unsigned* MX  = (unsigned*)((char*)LG + (size_t)E*4);
  float*    DN  = (float*)((char*)MX + (size_t)N*4);
  double*   STD = (double*)(wsb + oSTD);
  float*    STF = (float*)(wsb + oSTF);

  const double invN = 1.0 / (double)N;

  hipMemsetAsync(STD, 0, 16384*8, stream);
  hipMemsetAsync(AG, 0, szN128, stream);

  // ---- input projection + BN-in + relu -> L0 ----
  k_inproj<<<(N + 127)/128, 128, 0, stream>>>(x, W_in, b_in, L0, STD_BN(STD,0), N);
  k_bnfin<<<1, 128, 0, stream>>>(STD_BN(STD,0), g_in, beta_in, STF + 0, 0, invN);
  {
    long t4 = (long)N*32;
    k_affrelu<<<(unsigned)((t4 + 255)/256), 256, 0, stream>>>(L0, STF + 0, t4);
  }

  // ---- GINE edge scatter ----
  {
    long tot = (long)E*128;
    k_gine_edge<<<(unsigned)((tot + 255)/256), 256, 0, stream>>>(srcv, dstv, eattr, We, be, L0, AG, tot);
  }

  // ---- GINE MLP in two K-halves (y1 col-halves) ----
  dim3 gg((N + 63)/64, 2);
  // half 0
  k_gemm_gine1<<<gg, 256, 0, stream>>>(L0, AG, W1, b1, Y1h, STD_BN(STD,1), 0, N);
  k_bnfin<<<1, 128, 0, stream>>>(STD_BN(STD,1), g1, beta1, STF + 512, 0, invN);
  k_gemm_gine2a<<<gg, 256, 0, stream>>>(Y1h, STF, W2, P1, N, 0);
  // half 1
  k_gemm_gine1<<<gg, 256, 0, stream>>>(L0, AG, W1, b1, Y1h, STD_BN(STD,1), 128, N);
  k_bnfin<<<1, 128, 0, stream>>>(STD_BN(STD,1), g1, beta1, STF + 512, 128, invN);
  k_gemm_gine2b<<<gg, 256, 0, stream>>>(Y1h, STF, W2, b2, L0, skip0, P1, STD_BN(STD,2), N, 128);
  k_bnfin<<<1, 128, 0, stream>>>(STD_BN(STD,2), g_n0, b_n0, STF + 1024, 0, invN);

  // AG becomes the GAT output accumulator
  hipMemsetAsync(AG, 0, szN128, stream);

  // ---- GAT: head-by-head; xr in two 64-wide d-halves ----
  const int nb = (N + 63)/64;
  for (int h = 0; h < 4; ++h) {
    hipMemsetAsync(MX, 0, (size_t)N*4*2, stream);   // MX + DN contiguous
    // XL full [N,128] for this head
    k_gemm_gat<<<dim3(nb,1), 256, 0, stream>>>(P1, STF, Wl, bl, XL, N, h*128 + 0,  128, 0);
    k_gemm_gat<<<dim3(nb,1), 256, 0, stream>>>(P1, STF, Wl, bl, XL, N, h*128 + 64, 128, 64);
    for (int dh = 0; dh < 2; ++dh) {
      k_gemm_gat<<<dim3(nb,1), 256, 0, stream>>>(P1, STF, Wr, br, XRh, N, h*128 + dh*64, 64, 0);
      k_gat_logit_half<<<(E + 3)/4, 256, 0, stream>>>(srcv, dstv, eattr, XL, XRh, Weg, att,
                                                      LG, MX, E, h, dh);
    }
    k_gat_expdenh<<<(E + 255)/256, 256, 0, stream>>>(dstv, LG, MX, DN, E);
    k_gat_scath<<<(E + 3)/4, 256, 0, stream>>>(srcv, dstv, LG, DN, XL, AG, E);
  }

  // ---- post + BN n1 + final ----
  k_gat_post<<<(N + 255)/256, 128, 0, stream>>>(AG, P1, STF, bias_g, skip1, STD_BN(STD,3), N);
  k_bnfin<<<1, 128, 0, stream>>>(STD_BN(STD,3), g_n1, b_n1, STF + 1536, 0, invN);
  {
    long t4 = (long)N*32;
    k_final<<<(unsigned)((t4 + 255)/256), 256, 0, stream>>>(L0, P1, AG, STF, t4);
  }
  (void)n_in; (void)out_size; (void)ws_size;
}

// Round 5
// 1915.965 us; speedup vs baseline: 1.4185x; 1.4185x over previous
//
#include <hip/hip_runtime.h>
#include <stdint.h>

// ---------------- helpers ----------------
__device__ __forceinline__ float relu_(float v){ return v > 0.f ? v : 0.f; }

// ---------------- STD (f64 stats): 4 BN regions x [8 slices][2][256] doubles ----
// region stride 4096 doubles; sum at slice*512+col, sqs at slice*512+256+col
// BN idx: 0=input, 1=mlp(256col), 2=n0, 3=n1
#define STD_BN(p, idx) ((p) + (size_t)(idx) * 4096)
// STF (f32): a/b pairs: in@0, mlp@512, n0@1024, n1@1536 (a base+0..255, b base+256..511)

// ============ CSR build ============
__global__ __launch_bounds__(256) void k_hist(const int* __restrict__ dst,
                                              int* __restrict__ cnt, int E)
{
  int e = blockIdx.x*256 + threadIdx.x;
  if (e < E) atomicAdd(&cnt[dst[e]], 1);
}

__global__ __launch_bounds__(256) void k_scan1(const int* __restrict__ cnt,
    int* __restrict__ off, int* __restrict__ bsum, int N)
{
  __shared__ int part[256];
  int tid = threadIdx.x;
  int base = blockIdx.x*1024 + tid*4;
  int v[4]; int s = 0;
  #pragma unroll
  for (int j = 0; j < 4; ++j) { v[j] = (base + j < N) ? cnt[base + j] : 0; s += v[j]; }
  part[tid] = s;
  __syncthreads();
  #pragma unroll
  for (int d = 1; d < 256; d <<= 1) {
    int tv = (tid >= d) ? part[tid - d] : 0;
    __syncthreads();
    part[tid] += tv;
    __syncthreads();
  }
  int run = part[tid] - s;   // exclusive prefix for this thread
  #pragma unroll
  for (int j = 0; j < 4; ++j) {
    run += v[j];
    if (base + j < N) off[base + j + 1] = run;
  }
  if (tid == 255) bsum[blockIdx.x] = part[255];
}

__global__ void k_scan2(const int* __restrict__ bsum, int* __restrict__ bofs, int nb)
{
  if (threadIdx.x == 0) {
    int run = 0;
    for (int b = 0; b < nb; ++b) { bofs[b] = run; run += bsum[b]; }
  }
}

__global__ __launch_bounds__(256) void k_scan3(int* __restrict__ off,
    const int* __restrict__ bofs, int N)
{
  int tid = threadIdx.x;
  int base = blockIdx.x*1024 + tid*4;
  int add = bofs[blockIdx.x];
  #pragma unroll
  for (int j = 0; j < 4; ++j)
    if (base + j < N) off[base + j + 1] += add;
  if (blockIdx.x == 0 && tid == 0) off[0] = 0;
}

__global__ __launch_bounds__(256) void k_fill(const int* __restrict__ dst,
    const int* __restrict__ off, int* __restrict__ fill,
    int* __restrict__ eid, int E)
{
  int e = blockIdx.x*256 + threadIdx.x;
  if (e >= E) return;
  int t = dst[e];
  int pos = off[t] + atomicAdd(&fill[t], 1);
  eid[pos] = e;
}

// ============ input projection ============
__global__ __launch_bounds__(128) void k_inproj(
    const float* __restrict__ x, const float* __restrict__ W_in,
    const float* __restrict__ b_in, float* __restrict__ y0,
    double* __restrict__ STD0, int N)
{
  const int d = threadIdx.x;
  float w[10];
  #pragma unroll
  for (int k = 0; k < 10; ++k) w[k] = W_in[k*128 + d];
  const float bi = b_in[d];
  int r0 = blockIdx.x * 128;
  int rend = min(r0 + 128, N);
  double sum = 0.0, sqs = 0.0;
  for (int r = r0; r < rend; ++r) {
    const float* xr = x + (size_t)r * 10;
    float acc = bi;
    #pragma unroll
    for (int k = 0; k < 10; ++k) acc += xr[k] * w[k];
    y0[(size_t)r*128 + d] = acc;
    double a = (double)acc;
    sum += a; sqs += a*a;
  }
  int slice = blockIdx.x & 7;
  atomicAdd(&STD0[slice*512 + d], sum);
  atomicAdd(&STD0[slice*512 + 256 + d], sqs);
}

// ---- BN finalize ----
__global__ void k_bnfin(const double* __restrict__ STDbn,
                        const float* __restrict__ g, const float* __restrict__ beta,
                        float* __restrict__ STFbn, int colofs, double invN)
{
  int col = colofs + threadIdx.x;
  double s = 0.0, q = 0.0;
  #pragma unroll
  for (int sl = 0; sl < 8; ++sl) {
    s += STDbn[sl*512 + col];
    q += STDbn[sl*512 + 256 + col];
  }
  double m = s * invN;
  double var = q * invN - m*m;
  double av = (double)g[col] / sqrt(var + 1e-5);
  STFbn[col] = (float)av;
  STFbn[256 + col] = (float)((double)beta[col] - m*av);
}

// ---- in-place affine + relu on f32 [N,128] ----
__global__ __launch_bounds__(256) void k_affrelu(float* __restrict__ buf,
    const float* __restrict__ STF0, long total4)
{
  long g = (long)blockIdx.x*256 + threadIdx.x;
  if (g >= total4) return;
  int d0 = (int)((g*4) & 127);
  float4 v = ((const float4*)buf)[g];
  float4 av = *(const float4*)(STF0 + d0);
  float4 bv = *(const float4*)(STF0 + 256 + d0);
  v.x = relu_(av.x*v.x + bv.x);
  v.y = relu_(av.y*v.y + bv.y);
  v.z = relu_(av.z*v.z + bv.z);
  v.w = relu_(av.w*v.w + bv.w);
  ((float4*)buf)[g] = v;
}

// ---- column stats over f32 [N,128] (8-sliced f64 atomics) ----
__global__ __launch_bounds__(256) void k_colstats(
  const float* __restrict__ p, double* __restrict__ STDr, int colofs, int N)
{
  int col = threadIdx.x & 127;
  int ro  = threadIdx.x >> 7;       // 0..1
  int r0 = blockIdx.x * 256;
  int rend = min(r0 + 256, N);
  double s = 0.0, q = 0.0;
  for (int r = r0 + ro; r < rend; r += 2) {
    double v = (double)p[(size_t)r*128 + col];
    s += v; q += v*v;
  }
  int slice = (blockIdx.x & 3)*2 + ro;
  atomicAdd(&STDr[slice*512 + colofs + col], s);
  atomicAdd(&STDr[slice*512 + 256 + colofs + col], q);
}

// ============ GINE aggregation (CSR gather, no atomics) ============
__global__ __launch_bounds__(256) void k_gine_gather(
  const int* __restrict__ off, const int* __restrict__ eid,
  const int* __restrict__ src, const float* __restrict__ eattr,
  const float* __restrict__ We, const float* __restrict__ be,
  const float* __restrict__ L0, float* __restrict__ AG, int N)
{
  int wv = threadIdx.x >> 6, lane = threadIdx.x & 63;
  int t = blockIdx.x*4 + wv;
  if (t >= N) return;
  int o0 = off[t], deg = off[t+1] - o0;
  float2 w2[5];
  #pragma unroll
  for (int i = 0; i < 5; ++i) w2[i] = *(const float2*)(We + i*128 + 2*lane);
  float2 be2 = *(const float2*)(be + 2*lane);
  float2 acc = make_float2(0.f, 0.f);
  for (int i = 0; i < deg; ++i) {
    int e = eid[o0 + i];
    int s = src[e];
    float2 xl2 = *(const float2*)(L0 + (size_t)s*128 + 2*lane);
    const float* ep = eattr + (size_t)e*5;
    float ex = be2.x, ey = be2.y;
    #pragma unroll
    for (int j = 0; j < 5; ++j) { float ea = ep[j]; ex += ea*w2[j].x; ey += ea*w2[j].y; }
    acc.x += relu_(xl2.x + ex);
    acc.y += relu_(xl2.y + ey);
  }
  *((float2*)(AG + (size_t)t*128) + lane) = acc;
}

// ============ GEMM (64 rows x 128 cols per block, 4x8 per thread) ============
// MODE 0: A = A0 + A1 (gine1);            epi: OUT = acc + bias
// MODE 1: A = relu(a*A0 + c) (gine2a);    epi: OUT = acc (raw)
// MODE 2: A = relu(a*A0 + c) (gine2b);    epi: OUT = s0*l0 + (1-s0)*relu(OUT + acc + bias)
// MODE 3: A = a*A0 + c (gat, no relu);    epi: OUT = acc + bias
// NOTE: W is the base of the 128 K-rows used — caller applies any row offset.
template<int MODE>
__global__ __launch_bounds__(256) void k_gemm(
  const float* __restrict__ A0, const float* __restrict__ A1,
  const float* __restrict__ STF, int stfofs,
  const float* __restrict__ W, int ldw, int cb,
  const float* __restrict__ bias, int bofs,
  const float* __restrict__ l0, const float* __restrict__ sk,
  float* __restrict__ OUT, int N)
{
  __shared__ float As[64][68];
  const int tid = threadIdx.x;
  const int tx = tid & 15;        // col group: cols tx*8..+8
  const int ty = tid >> 4;        // row group: rows ty*4..+4
  const int row0 = blockIdx.x * 64;
  const int ar = tid >> 2, ac = tid & 3;
  float acc[4][8] = {};
  for (int kb = 0; kb < 128; kb += 64) {
    int r = row0 + ar;
    #pragma unroll
    for (int jj = 0; jj < 4; ++jj) {
      int kl = ac*16 + jj*4;
      int k = kb + kl;
      float4 v = make_float4(0.f,0.f,0.f,0.f);
      if (r < N) {
        if (MODE == 0) {
          float4 a4 = *(const float4*)(A0 + (size_t)r*128 + k);
          float4 g4 = *(const float4*)(A1 + (size_t)r*128 + k);
          v.x = a4.x+g4.x; v.y = a4.y+g4.y; v.z = a4.z+g4.z; v.w = a4.w+g4.w;
        } else {
          float4 t4 = *(const float4*)(A0 + (size_t)r*128 + k);
          float4 aa = *(const float4*)(STF + stfofs + k);
          float4 cc = *(const float4*)(STF + stfofs + 256 + k);
          v.x = aa.x*t4.x + cc.x; v.y = aa.y*t4.y + cc.y;
          v.z = aa.z*t4.z + cc.z; v.w = aa.w*t4.w + cc.w;
          if (MODE != 3) { v.x = relu_(v.x); v.y = relu_(v.y); v.z = relu_(v.z); v.w = relu_(v.w); }
        }
      }
      As[kl+0][ar]=v.x; As[kl+1][ar]=v.y; As[kl+2][ar]=v.z; As[kl+3][ar]=v.w;
    }
    __syncthreads();
    #pragma unroll 8
    for (int k = 0; k < 64; ++k) {
      float4 a = *(const float4*)&As[k][ty*4];
      const float* bp = W + (size_t)(kb+k)*ldw + cb + tx*8;
      float4 b0 = *(const float4*)bp;
      float4 b1 = *(const float4*)(bp + 4);
      float av[4] = {a.x,a.y,a.z,a.w};
      float bv[8] = {b0.x,b0.y,b0.z,b0.w,b1.x,b1.y,b1.z,b1.w};
      #pragma unroll
      for (int i = 0; i < 4; ++i)
        #pragma unroll
        for (int j = 0; j < 8; ++j) acc[i][j] += av[i]*bv[j];
    }
    __syncthreads();
  }
  float bv8[8] = {0,0,0,0,0,0,0,0};
  if (MODE != 1) {
    float4 bb0 = *(const float4*)(bias + bofs + tx*8);
    float4 bb1 = *(const float4*)(bias + bofs + tx*8 + 4);
    bv8[0]=bb0.x; bv8[1]=bb0.y; bv8[2]=bb0.z; bv8[3]=bb0.w;
    bv8[4]=bb1.x; bv8[5]=bb1.y; bv8[6]=bb1.z; bv8[7]=bb1.w;
  }
  float s0g = 0.f, os0 = 0.f;
  if (MODE == 2) { s0g = 1.f/(1.f + expf(-sk[0])); os0 = 1.f - s0g; }
  #pragma unroll
  for (int i = 0; i < 4; ++i) {
    int r = row0 + ty*4 + i;
    if (r < N) {
      float* orow = OUT + (size_t)r*128 + tx*8;
      float o[8];
      if (MODE == 2) {
        float4 p0 = *(const float4*)orow;
        float4 p1 = *(const float4*)(orow + 4);
        const float* lrow = l0 + (size_t)r*128 + tx*8;
        float4 l0a = *(const float4*)lrow;
        float4 l0b = *(const float4*)(lrow + 4);
        float pv[8] = {p0.x,p0.y,p0.z,p0.w,p1.x,p1.y,p1.z,p1.w};
        float lv[8] = {l0a.x,l0a.y,l0a.z,l0a.w,l0b.x,l0b.y,l0b.z,l0b.w};
        #pragma unroll
        for (int j = 0; j < 8; ++j)
          o[j] = s0g*lv[j] + os0*relu_(pv[j] + acc[i][j] + bv8[j]);
      } else if (MODE == 1) {
        #pragma unroll
        for (int j = 0; j < 8; ++j) o[j] = acc[i][j];
      } else {
        #pragma unroll
        for (int j = 0; j < 8; ++j) o[j] = acc[i][j] + bv8[j];
      }
      *(float4*)orow       = make_float4(o[0],o[1],o[2],o[3]);
      *(float4*)(orow + 4) = make_float4(o[4],o[5],o[6],o[7]);
    }
  }
}

// ============ fused GAT attention per head (CSR, no atomics) ============
#define GCAP 12

#define GAT_EDGE(IDX, POUT, XLOUT) { \
  int e_ = eid[o0 + (IDX)]; int s_ = src[e_]; \
  XLOUT = *(const float2*)(XL + (size_t)s_*128 + 2*lane); \
  const float* ep_ = eattr + (size_t)e_*5; \
  float fx_ = XLOUT.x + xr2.x, fy_ = XLOUT.y + xr2.y; \
  _Pragma("unroll") \
  for (int j5_ = 0; j5_ < 5; ++j5_) { float ea_ = ep_[j5_]; fx_ += ea_*w2[j5_].x; fy_ += ea_*w2[j5_].y; } \
  fx_ = fx_ > 0.f ? fx_ : 0.2f*fx_; \
  fy_ = fy_ > 0.f ? fy_ : 0.2f*fy_; \
  float pp_ = fx_*at2.x + fy_*at2.y; \
  _Pragma("unroll") \
  for (int mm_ = 1; mm_ < 64; mm_ <<= 1) pp_ += __shfl_xor(pp_, mm_, 64); \
  POUT = pp_; }

__global__ __launch_bounds__(256) void k_gat_attn(
  const int* __restrict__ off, const int* __restrict__ eid,
  const int* __restrict__ src, const float* __restrict__ eattr,
  const float* __restrict__ XL, const float* __restrict__ XR,
  const float* __restrict__ Weg, const float* __restrict__ att,
  float* __restrict__ AG, int N, int h, int first)
{
  __shared__ float2 xbuf[4][GCAP][64];
  int wv = threadIdx.x >> 6, lane = threadIdx.x & 63;
  int t = blockIdx.x*4 + wv;
  if (t >= N) return;
  int o0 = off[t], deg = off[t+1] - o0;
  float2* AGrow = (float2*)(AG + (size_t)t*128) + lane;
  if (deg == 0) { if (first) *AGrow = make_float2(0.f, 0.f); return; }
  int dcol = h*128 + 2*lane;
  float2 xr2 = *(const float2*)(XR + (size_t)t*128 + 2*lane);
  float2 at2 = *(const float2*)(att + dcol);
  float2 w2[5];
  #pragma unroll
  for (int i = 0; i < 5; ++i) w2[i] = *(const float2*)(Weg + i*512 + dcol);
  float mx = -1e30f;
  if (deg <= GCAP) {
    float lg[GCAP];
    #pragma unroll
    for (int i = 0; i < GCAP; ++i) {
      if (i < deg) {
        float p; float2 xl2;
        GAT_EDGE(i, p, xl2);
        xbuf[wv][i][lane] = xl2;
        lg[i] = p;
        mx = fmaxf(mx, p);
      }
    }
    float den = 0.f;
    #pragma unroll
    for (int i = 0; i < GCAP; ++i)
      if (i < deg) { lg[i] = expf(lg[i] - mx); den += lg[i]; }
    float sc = 0.25f / den;
    float2 acc = make_float2(0.f, 0.f);
    #pragma unroll
    for (int i = 0; i < GCAP; ++i)
      if (i < deg) {
        float2 xv = xbuf[wv][i][lane];
        acc.x += lg[i]*xv.x; acc.y += lg[i]*xv.y;
      }
    float2 prev = first ? make_float2(0.f,0.f) : *AGrow;
    *AGrow = make_float2(prev.x + sc*acc.x, prev.y + sc*acc.y);
  } else {
    // rare slow path: stream 3x, recompute logits
    for (int i = 0; i < deg; ++i) { float p; float2 xl2; GAT_EDGE(i, p, xl2); mx = fmaxf(mx, p); (void)xl2; }
    float den = 0.f;
    for (int i = 0; i < deg; ++i) { float p; float2 xl2; GAT_EDGE(i, p, xl2); den += expf(p - mx); (void)xl2; }
    float sc = 0.25f / den;
    float2 acc = make_float2(0.f, 0.f);
    for (int i = 0; i < deg; ++i) {
      float p; float2 xl2; GAT_EDGE(i, p, xl2);
      float al = expf(p - mx);
      acc.x += al*xl2.x; acc.y += al*xl2.y;
    }
    float2 prev = first ? make_float2(0.f,0.f) : *AGrow;
    *AGrow = make_float2(prev.x + sc*acc.x, prev.y + sc*acc.y);
  }
}

// ---- GAT post ----
__global__ __launch_bounds__(128) void k_gat_post(
  float* __restrict__ AG, const float* __restrict__ P1,
  const float* __restrict__ STF, const float* __restrict__ bias_gat,
  const float* __restrict__ skip1, double* __restrict__ STD3, int N)
{
  int d = threadIdx.x;
  float an0 = STF[1024 + d], bn0 = STF[1280 + d];
  float bg = bias_gat[d];
  float s1g = 1.f/(1.f + expf(-skip1[0]));
  float os1 = 1.f - s1g;
  int r0 = blockIdx.x * 256;
  int rend = min(r0 + 256, N);
  double sum = 0.0, sqs = 0.0;
  for (int r = r0; r < rend; ++r) {
    size_t idx = (size_t)r*128 + d;
    float xn = relu_(AG[idx] + bg);
    float l1 = an0*P1[idx] + bn0;
    float p2 = s1g*l1 + os1*xn;
    AG[idx] = p2;
    double dv = (double)p2;
    sum += dv; sqs += dv*dv;
  }
  int slice = blockIdx.x & 7;
  atomicAdd(&STD3[slice*512 + d], sum);
  atomicAdd(&STD3[slice*512 + 256 + d], sqs);
}

// ---- final ----
__global__ __launch_bounds__(256) void k_final(
  float* __restrict__ L0, const float* __restrict__ P1,
  const float* __restrict__ pre2, const float* __restrict__ STF, long total4)
{
  long g = (long)blockIdx.x*256 + threadIdx.x;
  if (g >= total4) return;
  int d0 = (int)((g*4) & 127);
  float4 a0 = *(const float4*)(STF + 1024 + d0);
  float4 b0 = *(const float4*)(STF + 1280 + d0);
  float4 a1 = *(const float4*)(STF + 1536 + d0);
  float4 b1 = *(const float4*)(STF + 1792 + d0);
  float4 v0 = ((const float4*)L0)[g];
  float4 v1 = ((const float4*)P1)[g];
  float4 v2 = ((const float4*)pre2)[g];
  float4 o;
  const float k3 = 1.f/3.f;
  o.x = (v0.x + (a0.x*v1.x + b0.x) + (a1.x*v2.x + b1.x)) * k3;
  o.y = (v0.y + (a0.y*v1.y + b0.y) + (a1.y*v2.y + b1.y)) * k3;
  o.z = (v0.z + (a0.z*v1.z + b0.z) + (a1.z*v2.z + b1.z)) * k3;
  o.w = (v0.w + (a0.w*v1.w + b0.w) + (a1.w*v2.w + b1.w)) * k3;
  ((float4*)L0)[g] = o;
}

// ---------------- host launch ----------------
extern "C" void kernel_launch(void* const* d_in, const int* in_sizes, int n_in,
                              void* d_out, int out_size, void* d_ws, size_t ws_size,
                              hipStream_t stream)
{
  const float* x       = (const float*)d_in[0];
  const int*   eidx    = (const int*)  d_in[1];
  const float* eattr   = (const float*)d_in[2];
  const float* W_in    = (const float*)d_in[4];
  const float* b_in    = (const float*)d_in[5];
  const float* g_in    = (const float*)d_in[6];
  const float* beta_in = (const float*)d_in[7];
  const float* We      = (const float*)d_in[8];
  const float* be      = (const float*)d_in[9];
  const float* W1      = (const float*)d_in[10];
  const float* b1      = (const float*)d_in[11];
  const float* g1      = (const float*)d_in[12];
  const float* beta1   = (const float*)d_in[13];
  const float* W2      = (const float*)d_in[14];
  const float* b2      = (const float*)d_in[15];
  const float* skip0   = (const float*)d_in[16];
  const float* skip1   = (const float*)d_in[17];
  const float* g_n0    = (const float*)d_in[18];
  const float* b_n0    = (const float*)d_in[19];
  const float* g_n1    = (const float*)d_in[20];
  const float* b_n1    = (const float*)d_in[21];
  const float* Wl      = (const float*)d_in[22];
  const float* bl      = (const float*)d_in[23];
  const float* Wr      = (const float*)d_in[24];
  const float* br      = (const float*)d_in[25];
  const float* att     = (const float*)d_in[26];
  const float* Weg     = (const float*)d_in[27];
  const float* bias_g  = (const float*)d_in[28];

  const int N = in_sizes[0] / 10;
  const int E = in_sizes[1] / 2;
  const int* srcv = eidx;
  const int* dstv = eidx + E;

  float* L0 = (float*)d_out;                 // layer0 lives in d_out; finalized in place

  // ---- workspace layout (~207 MB) ----
  char* wsb = (char*)d_ws;
  const size_t szN128 = (size_t)N*128*4;
  size_t oSTD = 0;                           // 16384 doubles = 131072 B
  size_t oSTF = oSTD + 131072;               // 2048 floats  = 8192 B
  size_t oAG  = oSTF + 8192;                 // f32 [N,128]
  size_t oP1  = oAG + szN128;                // f32 [N,128]
  size_t oXL  = oP1 + szN128;                // f32 [N,128] (Y1h in GINE phase)
  size_t oXR  = oXL + szN128;                // f32 [N,128]
  size_t oCNT = oXR + szN128;                // int [N]
  size_t oFIL = oCNT + (size_t)N*4;          // int [N]
  size_t oOFF = oFIL + (size_t)N*4;          // int [N+1]
  size_t oEID = oOFF + (size_t)(N+1)*4;      // int [E]
  size_t oBS  = oEID + (size_t)E*4;          // int [256]
  size_t oBOF = oBS + 1024;                  // int [256]

  double* STD = (double*)(wsb + oSTD);
  float*  STF = (float*) (wsb + oSTF);
  float*  AG  = (float*) (wsb + oAG);
  float*  P1  = (float*) (wsb + oP1);
  float*  XL  = (float*) (wsb + oXL);   // also Y1h
  float*  XR  = (float*) (wsb + oXR);
  int*    CNT = (int*)   (wsb + oCNT);
  int*    FIL = (int*)   (wsb + oFIL);
  int*    OFF = (int*)   (wsb + oOFF);
  int*    EID = (int*)   (wsb + oEID);
  int*    BS  = (int*)   (wsb + oBS);
  int*    BOF = (int*)   (wsb + oBOF);

  const double invN = 1.0 / (double)N;
  const int nb = (N + 63)/64;
  const int nscan = (N + 1023)/1024;

  hipMemsetAsync(STD, 0, 131072, stream);
  hipMemsetAsync(CNT, 0, (size_t)N*4, stream);
  hipMemsetAsync(FIL, 0, (size_t)N*4, stream);

  // ---- CSR build (dst-sorted) ----
  k_hist <<<(E + 255)/256, 256, 0, stream>>>(dstv, CNT, E);
  k_scan1<<<nscan, 256, 0, stream>>>(CNT, OFF, BS, N);
  k_scan2<<<1, 64, 0, stream>>>(BS, BOF, nscan);
  k_scan3<<<nscan, 256, 0, stream>>>(OFF, BOF, N);
  k_fill <<<(E + 255)/256, 256, 0, stream>>>(dstv, OFF, FIL, EID, E);

  // ---- input projection + BN + relu -> L0 ----
  k_inproj<<<(N + 127)/128, 128, 0, stream>>>(x, W_in, b_in, L0, STD_BN(STD,0), N);
  k_bnfin<<<1, 128, 0, stream>>>(STD_BN(STD,0), g_in, beta_in, STF + 0, 0, invN);
  {
    long t4 = (long)N*32;
    k_affrelu<<<(unsigned)((t4 + 255)/256), 256, 0, stream>>>(L0, STF + 0, t4);
  }

  // ---- GINE aggregation (CSR gather) ----
  k_gine_gather<<<(N + 3)/4, 256, 0, stream>>>(OFF, EID, srcv, eattr, We, be, L0, AG, N);

  // ---- GINE MLP: two y1 column-halves ----
  // half 0  (y1 cols 0..127 -> W2 rows 0..127)
  k_gemm<0><<<nb, 256, 0, stream>>>(L0, AG, STF, 0, W1, 256, 0,   b1, 0,   nullptr, nullptr, XL, N);
  k_colstats<<<(N + 255)/256, 256, 0, stream>>>(XL, STD_BN(STD,1), 0, N);
  k_bnfin<<<1, 128, 0, stream>>>(STD_BN(STD,1), g1, beta1, STF + 512, 0, invN);
  k_gemm<1><<<nb, 256, 0, stream>>>(XL, nullptr, STF, 512, W2, 128, 0, nullptr, 0, nullptr, nullptr, P1, N);
  // half 1  (y1 cols 128..255 -> W2 rows 128..255: offset the W base!)
  k_gemm<0><<<nb, 256, 0, stream>>>(L0, AG, STF, 0, W1, 256, 128, b1, 128, nullptr, nullptr, XL, N);
  k_colstats<<<(N + 255)/256, 256, 0, stream>>>(XL, STD_BN(STD,1), 128, N);
  k_bnfin<<<1, 128, 0, stream>>>(STD_BN(STD,1), g1, beta1, STF + 512, 128, invN);
  k_gemm<2><<<nb, 256, 0, stream>>>(XL, nullptr, STF, 640, W2 + (size_t)128*128, 128, 0, b2, 0, L0, skip0, P1, N);

  // ---- BN n0 stats ----
  k_colstats<<<(N + 255)/256, 256, 0, stream>>>(P1, STD_BN(STD,2), 0, N);
  k_bnfin<<<1, 128, 0, stream>>>(STD_BN(STD,2), g_n0, b_n0, STF + 1024, 0, invN);

  // ---- GAT head-by-head ----
  for (int h = 0; h < 4; ++h) {
    k_gemm<3><<<nb, 256, 0, stream>>>(P1, nullptr, STF, 1024, Wl, 512, h*128, bl, h*128, nullptr, nullptr, XL, N);
    k_gemm<3><<<nb, 256, 0, stream>>>(P1, nullptr, STF, 1024, Wr, 512, h*128, br, h*128, nullptr, nullptr, XR, N);
    k_gat_attn<<<(N + 3)/4, 256, 0, stream>>>(OFF, EID, srcv, eattr, XL, XR, Weg, att, AG, N, h, (h == 0) ? 1 : 0);
  }

  // ---- post + BN n1 + final ----
  k_gat_post<<<(N + 255)/256, 128, 0, stream>>>(AG, P1, STF, bias_g, skip1, STD_BN(STD,3), N);
  k_bnfin<<<1, 128, 0, stream>>>(STD_BN(STD,3), g_n1, b_n1, STF + 1536, 0, invN);
  {
    long t4 = (long)N*32;
    k_final<<<(unsigned)((t4 + 255)/256), 256, 0, stream>>>(L0, P1, AG, STF, t4);
  }
  (void)n_in; (void)out_size; (void)ws_size;
}

// Round 6
// 1731.277 us; speedup vs baseline: 1.5698x; 1.1067x over previous
//
#include <hip/hip_runtime.h>
#include <stdint.h>

// ---------------- helpers ----------------
__device__ __forceinline__ float relu_(float v){ return v > 0.f ? v : 0.f; }

// ---------------- STD (f64 stats): 4 BN regions x [8 slices][2][256] doubles ----
// region stride 4096 doubles; sum at slice*512+col, sqs at slice*512+256+col
// BN idx: 0=input, 1=mlp(256col), 2=n0, 3=n1
#define STD_BN(p, idx) ((p) + (size_t)(idx) * 4096)
// STF (f32): a/b pairs: in@0, mlp@512, n0@1024, n1@1536 (a base+0..255, b base+256..511)

// ============ CSR build ============
__global__ __launch_bounds__(256) void k_hist(const int* __restrict__ dst,
                                              int* __restrict__ cnt, int E)
{
  int e = blockIdx.x*256 + threadIdx.x;
  if (e < E) atomicAdd(&cnt[dst[e]], 1);
}

__global__ __launch_bounds__(256) void k_scan1(const int* __restrict__ cnt,
    int* __restrict__ off, int* __restrict__ bsum, int N)
{
  __shared__ int part[256];
  int tid = threadIdx.x;
  int base = blockIdx.x*1024 + tid*4;
  int v[4]; int s = 0;
  #pragma unroll
  for (int j = 0; j < 4; ++j) { v[j] = (base + j < N) ? cnt[base + j] : 0; s += v[j]; }
  part[tid] = s;
  __syncthreads();
  #pragma unroll
  for (int d = 1; d < 256; d <<= 1) {
    int tv = (tid >= d) ? part[tid - d] : 0;
    __syncthreads();
    part[tid] += tv;
    __syncthreads();
  }
  int run = part[tid] - s;
  #pragma unroll
  for (int j = 0; j < 4; ++j) {
    run += v[j];
    if (base + j < N) off[base + j + 1] = run;
  }
  if (tid == 255) bsum[blockIdx.x] = part[255];
}

__global__ void k_scan2(const int* __restrict__ bsum, int* __restrict__ bofs, int nb)
{
  if (threadIdx.x == 0) {
    int run = 0;
    for (int b = 0; b < nb; ++b) { bofs[b] = run; run += bsum[b]; }
  }
}

__global__ __launch_bounds__(256) void k_scan3(int* __restrict__ off,
    const int* __restrict__ bofs, int N)
{
  int tid = threadIdx.x;
  int base = blockIdx.x*1024 + tid*4;
  int add = bofs[blockIdx.x];
  #pragma unroll
  for (int j = 0; j < 4; ++j)
    if (base + j < N) off[base + j + 1] += add;
  if (blockIdx.x == 0 && tid == 0) off[0] = 0;
}

__global__ __launch_bounds__(256) void k_fill(const int* __restrict__ dst,
    const int* __restrict__ off, int* __restrict__ fill,
    int* __restrict__ eid, int E)
{
  int e = blockIdx.x*256 + threadIdx.x;
  if (e >= E) return;
  int t = dst[e];
  int pos = off[t] + atomicAdd(&fill[t], 1);
  eid[pos] = e;
}

// ============ input projection (256 threads: 2-row parallel) ============
__global__ __launch_bounds__(256) void k_inproj(
    const float* __restrict__ x, const float* __restrict__ W_in,
    const float* __restrict__ b_in, float* __restrict__ y0,
    double* __restrict__ STD0, int N)
{
  const int d  = threadIdx.x & 127;
  const int ro = threadIdx.x >> 7;
  float w[10];
  #pragma unroll
  for (int k = 0; k < 10; ++k) w[k] = W_in[k*128 + d];
  const float bi = b_in[d];
  int r0 = blockIdx.x * 128;
  int rend = min(r0 + 128, N);
  double sum = 0.0, sqs = 0.0;
  for (int r = r0 + ro; r < rend; r += 2) {
    const float* xr = x + (size_t)r * 10;
    float acc = bi;
    #pragma unroll
    for (int k = 0; k < 10; ++k) acc += xr[k] * w[k];
    y0[(size_t)r*128 + d] = acc;
    double a = (double)acc;
    sum += a; sqs += a*a;
  }
  int slice = ((blockIdx.x & 3) << 1) | ro;
  atomicAdd(&STD0[slice*512 + d], sum);
  atomicAdd(&STD0[slice*512 + 256 + d], sqs);
}

// ---- BN finalize ----
__global__ void k_bnfin(const double* __restrict__ STDbn,
                        const float* __restrict__ g, const float* __restrict__ beta,
                        float* __restrict__ STFbn, int colofs, double invN)
{
  int col = colofs + threadIdx.x;
  double s = 0.0, q = 0.0;
  #pragma unroll
  for (int sl = 0; sl < 8; ++sl) {
    s += STDbn[sl*512 + col];
    q += STDbn[sl*512 + 256 + col];
  }
  double m = s * invN;
  double var = q * invN - m*m;
  double av = (double)g[col] / sqrt(var + 1e-5);
  STFbn[col] = (float)av;
  STFbn[256 + col] = (float)((double)beta[col] - m*av);
}

// ---- in-place affine + relu on f32 [N,128] ----
__global__ __launch_bounds__(256) void k_affrelu(float* __restrict__ buf,
    const float* __restrict__ STF0, long total4)
{
  long g = (long)blockIdx.x*256 + threadIdx.x;
  if (g >= total4) return;
  int d0 = (int)((g*4) & 127);
  float4 v = ((const float4*)buf)[g];
  float4 av = *(const float4*)(STF0 + d0);
  float4 bv = *(const float4*)(STF0 + 256 + d0);
  v.x = relu_(av.x*v.x + bv.x);
  v.y = relu_(av.y*v.y + bv.y);
  v.z = relu_(av.z*v.z + bv.z);
  v.w = relu_(av.w*v.w + bv.w);
  ((float4*)buf)[g] = v;
}

// ---- column stats: C = row stride = #cols; 64 rows per block ----
template<int C>
__global__ __launch_bounds__(256) void k_colstats(
  const float* __restrict__ p, double* __restrict__ STDr, int N)
{
  int r0 = blockIdx.x * 64;
  int rend = min(r0 + 64, N);
  double s = 0.0, q = 0.0;
  int col, slice;
  if (C == 128) {
    col = threadIdx.x & 127;
    int ro = threadIdx.x >> 7;
    for (int r = r0 + ro; r < rend; r += 2) {
      double v = (double)p[(size_t)r*C + col];
      s += v; q += v*v;
    }
    slice = ((blockIdx.x & 3) << 1) | ro;
  } else {
    col = threadIdx.x;
    for (int r = r0; r < rend; ++r) {
      double v = (double)p[(size_t)r*C + col];
      s += v; q += v*v;
    }
    slice = blockIdx.x & 7;
  }
  atomicAdd(&STDr[slice*512 + col], s);
  atomicAdd(&STDr[slice*512 + 256 + col], q);
}

// ============ GINE aggregation (CSR gather, lane-parallel prefetch) ============
__global__ __launch_bounds__(256) void k_gine_gather(
  const int* __restrict__ off, const int* __restrict__ eid,
  const int* __restrict__ src, const float* __restrict__ eattr,
  const float* __restrict__ We, const float* __restrict__ be,
  const float* __restrict__ L0, float* __restrict__ AG, int N)
{
  int wv = threadIdx.x >> 6, lane = threadIdx.x & 63;
  int t = blockIdx.x*4 + wv;
  if (t >= N) return;
  int o0 = off[t], deg = off[t+1] - o0;
  float2 w2[5];
  #pragma unroll
  for (int i = 0; i < 5; ++i) w2[i] = *(const float2*)(We + i*128 + 2*lane);
  float2 be2 = *(const float2*)(be + 2*lane);
  float2 acc = make_float2(0.f, 0.f);
  for (int base = 0; base < deg; base += 64) {
    int cn = min(64, deg - base);
    int sL = 0; float eaL[5] = {0,0,0,0,0};
    if (lane < cn) {
      int eL = eid[o0 + base + lane];
      sL = src[eL];
      #pragma unroll
      for (int j = 0; j < 5; ++j) eaL[j] = eattr[(size_t)eL*5 + j];
    }
    for (int i = 0; i < cn; ++i) {
      int s_i = __shfl(sL, i);
      float2 xl2 = *(const float2*)(L0 + (size_t)s_i*128 + 2*lane);
      float ex = be2.x, ey = be2.y;
      #pragma unroll
      for (int j = 0; j < 5; ++j) {
        float ea = __shfl(eaL[j], i);
        ex += ea*w2[j].x; ey += ea*w2[j].y;
      }
      acc.x += relu_(xl2.x + ex);
      acc.y += relu_(xl2.y + ey);
    }
  }
  *((float2*)(AG + (size_t)t*128) + lane) = acc;
}

// ============ wide GEMM: A[N,128] -> OUT[N,256] (two 128-col halves) ============
// PREP 0: A = A0 + A1 (gine y1).   PREP 1: A = a*A0 + c (GAT, stfofs affine).
// Wa/Wb and ba/bb are caller-offset; both use leading dim ldw.
template<int PREP>
__global__ __launch_bounds__(256) void k_gemm_wide(
  const float* __restrict__ A0, const float* __restrict__ A1,
  const float* __restrict__ STF, int stfofs,
  const float* __restrict__ Wa, const float* __restrict__ Wb, int ldw,
  const float* __restrict__ ba, const float* __restrict__ bb,
  float* __restrict__ OUT, int N)
{
  __shared__ float As[64][68];
  const int tid = threadIdx.x;
  const int tx = tid & 15;        // cols tx*8..+8 in each half
  const int ty = tid >> 4;        // rows ty*4..+4
  const int row0 = blockIdx.x * 64;
  const int ar = tid >> 2, ac = tid & 3;
  float accL[4][8] = {}, accR[4][8] = {};
  for (int kb = 0; kb < 128; kb += 64) {
    int r = row0 + ar;
    #pragma unroll
    for (int jj = 0; jj < 4; ++jj) {
      int kl = ac*16 + jj*4;
      int k = kb + kl;
      float4 v = make_float4(0.f,0.f,0.f,0.f);
      if (r < N) {
        if (PREP == 0) {
          float4 a4 = *(const float4*)(A0 + (size_t)r*128 + k);
          float4 g4 = *(const float4*)(A1 + (size_t)r*128 + k);
          v.x = a4.x+g4.x; v.y = a4.y+g4.y; v.z = a4.z+g4.z; v.w = a4.w+g4.w;
        } else {
          float4 t4 = *(const float4*)(A0 + (size_t)r*128 + k);
          float4 aa = *(const float4*)(STF + stfofs + k);
          float4 cc = *(const float4*)(STF + stfofs + 256 + k);
          v.x = aa.x*t4.x + cc.x; v.y = aa.y*t4.y + cc.y;
          v.z = aa.z*t4.z + cc.z; v.w = aa.w*t4.w + cc.w;
        }
      }
      As[kl+0][ar]=v.x; As[kl+1][ar]=v.y; As[kl+2][ar]=v.z; As[kl+3][ar]=v.w;
    }
    __syncthreads();
    #pragma unroll 8
    for (int k = 0; k < 64; ++k) {
      float4 a = *(const float4*)&As[k][ty*4];
      const float* wra = Wa + (size_t)(kb+k)*ldw + tx*8;
      const float* wrb = Wb + (size_t)(kb+k)*ldw + tx*8;
      float4 La = *(const float4*)wra;
      float4 Lb = *(const float4*)(wra + 4);
      float4 Ra = *(const float4*)wrb;
      float4 Rb = *(const float4*)(wrb + 4);
      float av[4] = {a.x,a.y,a.z,a.w};
      float bl8[8] = {La.x,La.y,La.z,La.w,Lb.x,Lb.y,Lb.z,Lb.w};
      float br8[8] = {Ra.x,Ra.y,Ra.z,Ra.w,Rb.x,Rb.y,Rb.z,Rb.w};
      #pragma unroll
      for (int i = 0; i < 4; ++i)
        #pragma unroll
        for (int j = 0; j < 8; ++j) {
          accL[i][j] += av[i]*bl8[j];
          accR[i][j] += av[i]*br8[j];
        }
    }
    __syncthreads();
  }
  float4 ba0 = *(const float4*)(ba + tx*8);
  float4 ba1 = *(const float4*)(ba + tx*8 + 4);
  float4 bb0 = *(const float4*)(bb + tx*8);
  float4 bb1 = *(const float4*)(bb + tx*8 + 4);
  float bva[8] = {ba0.x,ba0.y,ba0.z,ba0.w,ba1.x,ba1.y,ba1.z,ba1.w};
  float bvb[8] = {bb0.x,bb0.y,bb0.z,bb0.w,bb1.x,bb1.y,bb1.z,bb1.w};
  #pragma unroll
  for (int i = 0; i < 4; ++i) {
    int r = row0 + ty*4 + i;
    if (r < N) {
      float* oL = OUT + (size_t)r*256 + tx*8;
      float* oR = oL + 128;
      *(float4*)oL       = make_float4(accL[i][0]+bva[0], accL[i][1]+bva[1], accL[i][2]+bva[2], accL[i][3]+bva[3]);
      *(float4*)(oL + 4) = make_float4(accL[i][4]+bva[4], accL[i][5]+bva[5], accL[i][6]+bva[6], accL[i][7]+bva[7]);
      *(float4*)oR       = make_float4(accR[i][0]+bvb[0], accR[i][1]+bvb[1], accR[i][2]+bvb[2], accR[i][3]+bvb[3]);
      *(float4*)(oR + 4) = make_float4(accR[i][4]+bvb[4], accR[i][5]+bvb[5], accR[i][6]+bvb[6], accR[i][7]+bvb[7]);
    }
  }
}

// ============ K=256 GEMM: P1 = s0*l0 + (1-s0)*relu( relu(a*Y2+c) @ W2 + b2 ) ============
__global__ __launch_bounds__(256) void k_gemm_k256(
  const float* __restrict__ Y2, const float* __restrict__ STF,
  const float* __restrict__ W2, const float* __restrict__ b2,
  const float* __restrict__ l0, const float* __restrict__ sk,
  float* __restrict__ P1, int N)
{
  __shared__ float As[64][68];
  const int tid = threadIdx.x;
  const int tx = tid & 15, ty = tid >> 4;
  const int row0 = blockIdx.x * 64;
  const int ar = tid >> 2, ac = tid & 3;
  float acc[4][8] = {};
  for (int kb = 0; kb < 256; kb += 64) {
    int r = row0 + ar;
    #pragma unroll
    for (int jj = 0; jj < 4; ++jj) {
      int kl = ac*16 + jj*4;
      int k = kb + kl;
      float4 v = make_float4(0.f,0.f,0.f,0.f);
      if (r < N) {
        float4 t4 = *(const float4*)(Y2 + (size_t)r*256 + k);
        float4 aa = *(const float4*)(STF + 512 + k);
        float4 cc = *(const float4*)(STF + 768 + k);
        v.x = relu_(aa.x*t4.x + cc.x);
        v.y = relu_(aa.y*t4.y + cc.y);
        v.z = relu_(aa.z*t4.z + cc.z);
        v.w = relu_(aa.w*t4.w + cc.w);
      }
      As[kl+0][ar]=v.x; As[kl+1][ar]=v.y; As[kl+2][ar]=v.z; As[kl+3][ar]=v.w;
    }
    __syncthreads();
    #pragma unroll 8
    for (int k = 0; k < 64; ++k) {
      float4 a = *(const float4*)&As[k][ty*4];
      const float* bp = W2 + (size_t)(kb+k)*128 + tx*8;
      float4 b0 = *(const float4*)bp;
      float4 b1 = *(const float4*)(bp + 4);
      float av[4] = {a.x,a.y,a.z,a.w};
      float bv[8] = {b0.x,b0.y,b0.z,b0.w,b1.x,b1.y,b1.z,b1.w};
      #pragma unroll
      for (int i = 0; i < 4; ++i)
        #pragma unroll
        for (int j = 0; j < 8; ++j) acc[i][j] += av[i]*bv[j];
    }
    __syncthreads();
  }
  float s0g = 1.f/(1.f + expf(-sk[0]));
  float os0 = 1.f - s0g;
  float4 c0 = *(const float4*)(b2 + tx*8);
  float4 c1 = *(const float4*)(b2 + tx*8 + 4);
  float bv8[8] = {c0.x,c0.y,c0.z,c0.w,c1.x,c1.y,c1.z,c1.w};
  #pragma unroll
  for (int i = 0; i < 4; ++i) {
    int r = row0 + ty*4 + i;
    if (r < N) {
      const float* lrow = l0 + (size_t)r*128 + tx*8;
      float4 l0a = *(const float4*)lrow;
      float4 l0b = *(const float4*)(lrow + 4);
      float lv[8] = {l0a.x,l0a.y,l0a.z,l0a.w,l0b.x,l0b.y,l0b.z,l0b.w};
      float o[8];
      #pragma unroll
      for (int j = 0; j < 8; ++j)
        o[j] = s0g*lv[j] + os0*relu_(acc[i][j] + bv8[j]);
      float* orow = P1 + (size_t)r*128 + tx*8;
      *(float4*)orow       = make_float4(o[0],o[1],o[2],o[3]);
      *(float4*)(orow + 4) = make_float4(o[4],o[5],o[6],o[7]);
    }
  }
}

// ============ fused GAT attention per head (registers only, prefetch) ============
#define GCAP 12

// slow-path per-edge macro (X2 layout: xl at +0, xr handled via xr2)
#define GAT_EDGE(IDX, POUT, XLOUT) { \
  int e_ = eid[o0 + (IDX)]; int s_ = src[e_]; \
  XLOUT = *(const float2*)(X2 + (size_t)s_*256 + 2*lane); \
  const float* ep_ = eattr + (size_t)e_*5; \
  float fx_ = XLOUT.x + xr2.x, fy_ = XLOUT.y + xr2.y; \
  _Pragma("unroll") \
  for (int j5_ = 0; j5_ < 5; ++j5_) { float ea_ = ep_[j5_]; fx_ += ea_*w2[j5_].x; fy_ += ea_*w2[j5_].y; } \
  fx_ = fx_ > 0.f ? fx_ : 0.2f*fx_; \
  fy_ = fy_ > 0.f ? fy_ : 0.2f*fy_; \
  float pp_ = fx_*at2.x + fy_*at2.y; \
  _Pragma("unroll") \
  for (int mm_ = 1; mm_ < 64; mm_ <<= 1) pp_ += __shfl_xor(pp_, mm_, 64); \
  POUT = pp_; }

__global__ __launch_bounds__(256) void k_gat_attn(
  const int* __restrict__ off, const int* __restrict__ eid,
  const int* __restrict__ src, const float* __restrict__ eattr,
  const float* __restrict__ X2, const float* __restrict__ Weg,
  const float* __restrict__ att, float* __restrict__ AG,
  int N, int h, int first)
{
  int wv = threadIdx.x >> 6, lane = threadIdx.x & 63;
  int t = blockIdx.x*4 + wv;
  if (t >= N) return;
  int o0 = off[t], deg = off[t+1] - o0;
  float2* AGrow = (float2*)(AG + (size_t)t*128) + lane;
  if (deg == 0) { if (first) *AGrow = make_float2(0.f, 0.f); return; }
  int dcol = h*128 + 2*lane;
  float2 xr2 = *(const float2*)(X2 + (size_t)t*256 + 128 + 2*lane);
  float2 at2 = *(const float2*)(att + dcol);
  float2 w2[5];
  #pragma unroll
  for (int i = 0; i < 5; ++i) w2[i] = *(const float2*)(Weg + i*512 + dcol);

  if (deg <= GCAP) {
    // lane-parallel prefetch of edge metadata
    int sL = 0; float eaL[5] = {0,0,0,0,0};
    if (lane < deg) {
      int eL = eid[o0 + lane];
      sL = src[eL];
      #pragma unroll
      for (int j = 0; j < 5; ++j) eaL[j] = eattr[(size_t)eL*5 + j];
    }
    float lg[GCAP]; float2 xb[GCAP];
    float mx = -1e30f;
    #pragma unroll
    for (int i = 0; i < GCAP; ++i) {
      if (i < deg) {
        int s_i = __shfl(sL, i);
        float2 xl2 = *(const float2*)(X2 + (size_t)s_i*256 + 2*lane);
        float fx = xl2.x + xr2.x, fy = xl2.y + xr2.y;
        #pragma unroll
        for (int j = 0; j < 5; ++j) {
          float ea = __shfl(eaL[j], i);
          fx += ea*w2[j].x; fy += ea*w2[j].y;
        }
        fx = fx > 0.f ? fx : 0.2f*fx;
        fy = fy > 0.f ? fy : 0.2f*fy;
        float p = fx*at2.x + fy*at2.y;
        #pragma unroll
        for (int m = 1; m < 64; m <<= 1) p += __shfl_xor(p, m, 64);
        lg[i] = p; xb[i] = xl2;
        mx = fmaxf(mx, p);
      }
    }
    float den = 0.f;
    #pragma unroll
    for (int i = 0; i < GCAP; ++i)
      if (i < deg) { lg[i] = expf(lg[i] - mx); den += lg[i]; }
    float sc = 0.25f / den;
    float2 acc = make_float2(0.f, 0.f);
    #pragma unroll
    for (int i = 0; i < GCAP; ++i)
      if (i < deg) { acc.x += lg[i]*xb[i].x; acc.y += lg[i]*xb[i].y; }
    float2 prev = first ? make_float2(0.f,0.f) : *AGrow;
    *AGrow = make_float2(prev.x + sc*acc.x, prev.y + sc*acc.y);
  } else {
    // rare slow path (deg > GCAP): stream 3x, recompute logits
    float mx = -1e30f;
    for (int i = 0; i < deg; ++i) { float p; float2 xl2; GAT_EDGE(i, p, xl2); mx = fmaxf(mx, p); (void)xl2; }
    float den = 0.f;
    for (int i = 0; i < deg; ++i) { float p; float2 xl2; GAT_EDGE(i, p, xl2); den += expf(p - mx); (void)xl2; }
    float sc = 0.25f / den;
    float2 acc = make_float2(0.f, 0.f);
    for (int i = 0; i < deg; ++i) {
      float p; float2 xl2; GAT_EDGE(i, p, xl2);
      float al = expf(p - mx);
      acc.x += al*xl2.x; acc.y += al*xl2.y;
    }
    float2 prev = first ? make_float2(0.f,0.f) : *AGrow;
    *AGrow = make_float2(prev.x + sc*acc.x, prev.y + sc*acc.y);
  }
}

// ---- GAT post ----
__global__ __launch_bounds__(128) void k_gat_post(
  float* __restrict__ AG, const float* __restrict__ P1,
  const float* __restrict__ STF, const float* __restrict__ bias_gat,
  const float* __restrict__ skip1, double* __restrict__ STD3, int N)
{
  int d = threadIdx.x;
  float an0 = STF[1024 + d], bn0 = STF[1280 + d];
  float bg = bias_gat[d];
  float s1g = 1.f/(1.f + expf(-skip1[0]));
  float os1 = 1.f - s1g;
  int r0 = blockIdx.x * 256;
  int rend = min(r0 + 256, N);
  double sum = 0.0, sqs = 0.0;
  for (int r = r0; r < rend; ++r) {
    size_t idx = (size_t)r*128 + d;
    float xn = relu_(AG[idx] + bg);
    float l1 = an0*P1[idx] + bn0;
    float p2 = s1g*l1 + os1*xn;
    AG[idx] = p2;
    double dv = (double)p2;
    sum += dv; sqs += dv*dv;
  }
  int slice = blockIdx.x & 7;
  atomicAdd(&STD3[slice*512 + d], sum);
  atomicAdd(&STD3[slice*512 + 256 + d], sqs);
}

// ---- final ----
__global__ __launch_bounds__(256) void k_final(
  float* __restrict__ L0, const float* __restrict__ P1,
  const float* __restrict__ pre2, const float* __restrict__ STF, long total4)
{
  long g = (long)blockIdx.x*256 + threadIdx.x;
  if (g >= total4) return;
  int d0 = (int)((g*4) & 127);
  float4 a0 = *(const float4*)(STF + 1024 + d0);
  float4 b0 = *(const float4*)(STF + 1280 + d0);
  float4 a1 = *(const float4*)(STF + 1536 + d0);
  float4 b1 = *(const float4*)(STF + 1792 + d0);
  float4 v0 = ((const float4*)L0)[g];
  float4 v1 = ((const float4*)P1)[g];
  float4 v2 = ((const float4*)pre2)[g];
  float4 o;
  const float k3 = 1.f/3.f;
  o.x = (v0.x + (a0.x*v1.x + b0.x) + (a1.x*v2.x + b1.x)) * k3;
  o.y = (v0.y + (a0.y*v1.y + b0.y) + (a1.y*v2.y + b1.y)) * k3;
  o.z = (v0.z + (a0.z*v1.z + b0.z) + (a1.z*v2.z + b1.z)) * k3;
  o.w = (v0.w + (a0.w*v1.w + b0.w) + (a1.w*v2.w + b1.w)) * k3;
  ((float4*)L0)[g] = o;
}

// ---------------- host launch ----------------
extern "C" void kernel_launch(void* const* d_in, const int* in_sizes, int n_in,
                              void* d_out, int out_size, void* d_ws, size_t ws_size,
                              hipStream_t stream)
{
  const float* x       = (const float*)d_in[0];
  const int*   eidx    = (const int*)  d_in[1];
  const float* eattr   = (const float*)d_in[2];
  const float* W_in    = (const float*)d_in[4];
  const float* b_in    = (const float*)d_in[5];
  const float* g_in    = (const float*)d_in[6];
  const float* beta_in = (const float*)d_in[7];
  const float* We      = (const float*)d_in[8];
  const float* be      = (const float*)d_in[9];
  const float* W1      = (const float*)d_in[10];
  const float* b1      = (const float*)d_in[11];
  const float* g1      = (const float*)d_in[12];
  const float* beta1   = (const float*)d_in[13];
  const float* W2      = (const float*)d_in[14];
  const float* b2      = (const float*)d_in[15];
  const float* skip0   = (const float*)d_in[16];
  const float* skip1   = (const float*)d_in[17];
  const float* g_n0    = (const float*)d_in[18];
  const float* b_n0    = (const float*)d_in[19];
  const float* g_n1    = (const float*)d_in[20];
  const float* b_n1    = (const float*)d_in[21];
  const float* Wl      = (const float*)d_in[22];
  const float* bl      = (const float*)d_in[23];
  const float* Wr      = (const float*)d_in[24];
  const float* br      = (const float*)d_in[25];
  const float* att     = (const float*)d_in[26];
  const float* Weg     = (const float*)d_in[27];
  const float* bias_g  = (const float*)d_in[28];

  const int N = in_sizes[0] / 10;
  const int E = in_sizes[1] / 2;
  const int* srcv = eidx;
  const int* dstv = eidx + E;

  float* L0 = (float*)d_out;                 // layer0 lives in d_out; finalized in place

  // ---- workspace layout (~207 MB) ----
  char* wsb = (char*)d_ws;
  const size_t szN128 = (size_t)N*128*4;
  size_t oSTD = 0;                           // 16384 doubles = 131072 B
  size_t oSTF = oSTD + 131072;               // 2048 floats
  size_t oAG  = oSTF + 8192;                 // f32 [N,128]
  size_t oP1  = oAG + szN128;                // f32 [N,128]
  size_t oX2  = oP1 + szN128;                // f32 [N,256]: y1 (GINE) / xl|xr (GAT)
  size_t oCNT = oX2 + 2*szN128;              // int [N]
  size_t oFIL = oCNT + (size_t)N*4;          // int [N]
  size_t oOFF = oFIL + (size_t)N*4;          // int [N+1]
  size_t oEID = oOFF + (size_t)(N+1)*4;      // int [E]
  size_t oBS  = oEID + (size_t)E*4;          // int [256]
  size_t oBOF = oBS + 1024;                  // int [256]

  double* STD = (double*)(wsb + oSTD);
  float*  STF = (float*) (wsb + oSTF);
  float*  AG  = (float*) (wsb + oAG);
  float*  P1  = (float*) (wsb + oP1);
  float*  X2  = (float*) (wsb + oX2);
  int*    CNT = (int*)   (wsb + oCNT);
  int*    FIL = (int*)   (wsb + oFIL);
  int*    OFF = (int*)   (wsb + oOFF);
  int*    EID = (int*)   (wsb + oEID);
  int*    BS  = (int*)   (wsb + oBS);
  int*    BOF = (int*)   (wsb + oBOF);

  const double invN = 1.0 / (double)N;
  const int nb = (N + 63)/64;
  const int nscan = (N + 1023)/1024;

  hipMemsetAsync(STD, 0, 131072, stream);
  hipMemsetAsync(CNT, 0, (size_t)N*4, stream);
  hipMemsetAsync(FIL, 0, (size_t)N*4, stream);

  // ---- CSR build (dst-sorted) ----
  k_hist <<<(E + 255)/256, 256, 0, stream>>>(dstv, CNT, E);
  k_scan1<<<nscan, 256, 0, stream>>>(CNT, OFF, BS, N);
  k_scan2<<<1, 64, 0, stream>>>(BS, BOF, nscan);
  k_scan3<<<nscan, 256, 0, stream>>>(OFF, BOF, N);
  k_fill <<<(E + 255)/256, 256, 0, stream>>>(dstv, OFF, FIL, EID, E);

  // ---- input projection + BN + relu -> L0 ----
  k_inproj<<<(N + 127)/128, 256, 0, stream>>>(x, W_in, b_in, L0, STD_BN(STD,0), N);
  k_bnfin<<<1, 128, 0, stream>>>(STD_BN(STD,0), g_in, beta_in, STF + 0, 0, invN);
  {
    long t4 = (long)N*32;
    k_affrelu<<<(unsigned)((t4 + 255)/256), 256, 0, stream>>>(L0, STF + 0, t4);
  }

  // ---- GINE aggregation (CSR gather) ----
  k_gine_gather<<<(N + 3)/4, 256, 0, stream>>>(OFF, EID, srcv, eattr, We, be, L0, AG, N);

  // ---- GINE MLP ----
  // y1 [N,256] in one wide GEMM: cols 0..127 from W1[:, :128], cols 128..255 from W1[:, 128:]
  k_gemm_wide<0><<<nb, 256, 0, stream>>>(L0, AG, STF, 0, W1, W1 + 128, 256, b1, b1 + 128, X2, N);
  k_colstats<256><<<nb, 256, 0, stream>>>(X2, STD_BN(STD,1), N);
  k_bnfin<<<1, 256, 0, stream>>>(STD_BN(STD,1), g1, beta1, STF + 512, 0, invN);
  // P1 = s0*L0 + (1-s0)*relu( relu(BN(y1)) @ W2 + b2 )
  k_gemm_k256<<<nb, 256, 0, stream>>>(X2, STF, W2, b2, L0, skip0, P1, N);
  k_colstats<128><<<nb, 256, 0, stream>>>(P1, STD_BN(STD,2), N);
  k_bnfin<<<1, 128, 0, stream>>>(STD_BN(STD,2), g_n0, b_n0, STF + 1024, 0, invN);

  // ---- GAT head-by-head: one wide GEMM (xl|xr) + fused attention ----
  for (int h = 0; h < 4; ++h) {
    k_gemm_wide<1><<<nb, 256, 0, stream>>>(P1, nullptr, STF, 1024,
                                           Wl + h*128, Wr + h*128, 512,
                                           bl + h*128, br + h*128, X2, N);
    k_gat_attn<<<(N + 3)/4, 256, 0, stream>>>(OFF, EID, srcv, eattr, X2, Weg, att,
                                              AG, N, h, (h == 0) ? 1 : 0);
  }

  // ---- post + BN n1 + final ----
  k_gat_post<<<(N + 255)/256, 128, 0, stream>>>(AG, P1, STF, bias_g, skip1, STD_BN(STD,3), N);
  k_bnfin<<<1, 128, 0, stream>>>(STD_BN(STD,3), g_n1, b_n1, STF + 1536, 0, invN);
  {
    long t4 = (long)N*32;
    k_final<<<(unsigned)((t4 + 255)/256), 256, 0, stream>>>(L0, P1, AG, STF, t4);
  }
  (void)n_in; (void)out_size; (void)ws_size;
}

// Round 7
// 1259.813 us; speedup vs baseline: 2.1573x; 1.3742x over previous
//
#include <hip/hip_runtime.h>
#include <stdint.h>

// ---------------- helpers ----------------
__device__ __forceinline__ float relu_(float v){ return v > 0.f ? v : 0.f; }

typedef _Float16 f16;
typedef f16 f16x8 __attribute__((ext_vector_type(8)));
typedef float f32x4 __attribute__((ext_vector_type(4)));

__device__ __forceinline__ f16x8 u2h(uint4 u){ union{uint4 u; f16x8 h;} c; c.u=u; return c.h; }

// ---------------- STD (f64 stats): 4 BN regions x [8 slices][2][256] doubles ----
#define STD_BN(p, idx) ((p) + (size_t)(idx) * 4096)
// STF (f32): a/b pairs: in@0, mlp@512, n0@1024, n1@1536 (a base+0..255, b base+256..511)

// ============ CSR build ============
__global__ __launch_bounds__(256) void k_hist(const int* __restrict__ dst,
                                              int* __restrict__ cnt, int E)
{
  int e = blockIdx.x*256 + threadIdx.x;
  if (e < E) atomicAdd(&cnt[dst[e]], 1);
}

__global__ __launch_bounds__(256) void k_scan1(const int* __restrict__ cnt,
    int* __restrict__ off, int* __restrict__ bsum, int N)
{
  __shared__ int part[256];
  int tid = threadIdx.x;
  int base = blockIdx.x*1024 + tid*4;
  int v[4]; int s = 0;
  #pragma unroll
  for (int j = 0; j < 4; ++j) { v[j] = (base + j < N) ? cnt[base + j] : 0; s += v[j]; }
  part[tid] = s;
  __syncthreads();
  #pragma unroll
  for (int d = 1; d < 256; d <<= 1) {
    int tv = (tid >= d) ? part[tid - d] : 0;
    __syncthreads();
    part[tid] += tv;
    __syncthreads();
  }
  int run = part[tid] - s;
  #pragma unroll
  for (int j = 0; j < 4; ++j) {
    run += v[j];
    if (base + j < N) off[base + j + 1] = run;
  }
  if (tid == 255) bsum[blockIdx.x] = part[255];
}

__global__ void k_scan2(const int* __restrict__ bsum, int* __restrict__ bofs, int nb)
{
  if (threadIdx.x == 0) {
    int run = 0;
    for (int b = 0; b < nb; ++b) { bofs[b] = run; run += bsum[b]; }
  }
}

__global__ __launch_bounds__(256) void k_scan3(int* __restrict__ off,
    const int* __restrict__ bofs, int N)
{
  int tid = threadIdx.x;
  int base = blockIdx.x*1024 + tid*4;
  int add = bofs[blockIdx.x];
  #pragma unroll
  for (int j = 0; j < 4; ++j)
    if (base + j < N) off[base + j + 1] += add;
  if (blockIdx.x == 0 && tid == 0) off[0] = 0;
}

__global__ __launch_bounds__(256) void k_fill(const int* __restrict__ dst,
    const int* __restrict__ off, int* __restrict__ fill,
    int* __restrict__ eid, int E)
{
  int e = blockIdx.x*256 + threadIdx.x;
  if (e >= E) return;
  int t = dst[e];
  int pos = off[t] + atomicAdd(&fill[t], 1);
  eid[pos] = e;
}

// ============ weight pack: fragment-ordered f16 hi/lo ============
// Bpk element idx = ((ks*nctFull + ct0+ctl)*64 + lane)*2 + {0:hi,1:lo}
__global__ __launch_bounds__(64) void k_packB(
  const float* __restrict__ W, int ldw, int cb,
  int ct0, int nks, int nctFull, uint4* __restrict__ Bpk)
{
  int ks  = blockIdx.x % nks;
  int ctl = blockIdx.x / nks;
  int lane = threadIdx.x;
  int col = cb + ctl*16 + (lane & 15);
  int kbase = ks*32 + (lane >> 4)*8;
  f16x8 hi, lo;
  #pragma unroll
  for (int i = 0; i < 8; ++i) {
    float w = W[(size_t)(kbase + i)*ldw + col];
    f16 h = (f16)w;
    hi[i] = h;
    lo[i] = (f16)(w - (float)h);
  }
  union{f16x8 h; uint4 u;} ch, cl; ch.h = hi; cl.h = lo;
  size_t idx = ((size_t)(ks*nctFull + ct0 + ctl)*64 + lane)*2;
  Bpk[idx] = ch.u;
  Bpk[idx + 1] = cl.u;
}

// GAT bias pack: bp[h*256 + c] = c<128 ? bl[h*128+c] : br[h*128+c-128]
__global__ void k_packbias(const float* __restrict__ bl, const float* __restrict__ br,
                           float* __restrict__ bp)
{
  int c = threadIdx.x, h = blockIdx.x;
  bp[h*256 + c] = (c < 128) ? bl[h*128 + c] : br[h*128 + (c - 128)];
}

// ============ MFMA GEMM: 64 rows x NT cols per block, split-f16, f32 acc ============
// PREP 0: A = A0 + A1           (gine1,  K=128)
// PREP 1: A = relu(a*A0 + c)    (gine2,  K=256, stfofs=512)
// PREP 2: A = a*A0 + c          (gat,    K=128, stfofs=1024)
// EPI  0: OUT[row*NT+col] = acc + biasp[col]
// EPI  1: OUT = s0*l0 + (1-s0)*relu(acc + biasp[col])   (P1, NT=128)
template<int PREP, int EPI, int K, int NT>
__global__ __launch_bounds__(256) void k_mfma(
  const float* __restrict__ A0, const float* __restrict__ A1,
  const float* __restrict__ STF, int stfofs,
  const uint4* __restrict__ Bpk, const float* __restrict__ biasp,
  const float* __restrict__ l0, const float* __restrict__ sk,
  float* __restrict__ OUT, int N)
{
  __shared__ float As[64][68];
  constexpr int NCT = NT/16;
  const int tid = threadIdx.x;
  const int lane = tid & 63, wv = tid >> 6;
  const int fr = lane & 15, fg = lane >> 4;
  const int row0 = blockIdx.x * 64;
  f32x4 acc[NCT];
  #pragma unroll
  for (int ct = 0; ct < NCT; ++ct) acc[ct] = (f32x4){0.f, 0.f, 0.f, 0.f};

  const int sr = tid >> 2;          // staging row 0..63
  const int sc = (tid & 3) * 16;    // staging col base (16 floats)
  for (int kb = 0; kb < K; kb += 64) {
    int r = row0 + sr;
    #pragma unroll
    for (int j = 0; j < 4; ++j) {
      int c = sc + j*4;
      int k = kb + c;
      float4 v = make_float4(0.f, 0.f, 0.f, 0.f);
      if (r < N) {
        if (PREP == 0) {
          float4 a = *(const float4*)(A0 + (size_t)r*K + k);
          float4 b = *(const float4*)(A1 + (size_t)r*K + k);
          v.x = a.x+b.x; v.y = a.y+b.y; v.z = a.z+b.z; v.w = a.w+b.w;
        } else {
          float4 a  = *(const float4*)(A0 + (size_t)r*K + k);
          float4 aa = *(const float4*)(STF + stfofs + k);
          float4 cc = *(const float4*)(STF + stfofs + 256 + k);
          v.x = aa.x*a.x + cc.x; v.y = aa.y*a.y + cc.y;
          v.z = aa.z*a.z + cc.z; v.w = aa.w*a.w + cc.w;
          if (PREP == 1) { v.x=relu_(v.x); v.y=relu_(v.y); v.z=relu_(v.z); v.w=relu_(v.w); }
        }
      }
      *(float4*)&As[sr][c] = v;
    }
    __syncthreads();
    #pragma unroll
    for (int k2 = 0; k2 < 2; ++k2) {
      const float* ap = &As[wv*16 + fr][k2*32 + fg*8];
      f16x8 ah, al;
      #pragma unroll
      for (int i = 0; i < 8; ++i) {
        float a = ap[i];
        f16 h = (f16)a;
        ah[i] = h;
        al[i] = (f16)(a - (float)h);
      }
      int ks = (kb >> 5) + k2;
      const uint4* bp = Bpk + ((size_t)ks*NCT*64 + lane)*2;
      #pragma unroll
      for (int ct = 0; ct < NCT; ++ct) {
        f16x8 bh = u2h(bp[ct*128]);
        f16x8 bl = u2h(bp[ct*128 + 1]);
        acc[ct] = __builtin_amdgcn_mfma_f32_16x16x32_f16(ah, bh, acc[ct], 0, 0, 0);
        acc[ct] = __builtin_amdgcn_mfma_f32_16x16x32_f16(ah, bl, acc[ct], 0, 0, 0);
        acc[ct] = __builtin_amdgcn_mfma_f32_16x16x32_f16(al, bh, acc[ct], 0, 0, 0);
      }
    }
    __syncthreads();
  }
  // epilogue: D[row=(lane>>4)*4+rr][col=lane&15] per 16x16 tile (m89-verified)
  float s0g = 0.f, os0 = 0.f;
  if (EPI == 1) { s0g = 1.f/(1.f + expf(-sk[0])); os0 = 1.f - s0g; }
  #pragma unroll
  for (int ct = 0; ct < NCT; ++ct) {
    int col = ct*16 + fr;
    float bv = biasp[col];
    #pragma unroll
    for (int rr = 0; rr < 4; ++rr) {
      int row = row0 + wv*16 + fg*4 + rr;
      if (row < N) {
        float v = acc[ct][rr] + bv;
        if (EPI == 1) v = s0g*l0[(size_t)row*128 + col] + os0*relu_(v);
        OUT[(size_t)row*NT + col] = v;
      }
    }
  }
}

// ============ input projection (256 threads: 2-row parallel) ============
__global__ __launch_bounds__(256) void k_inproj(
    const float* __restrict__ x, const float* __restrict__ W_in,
    const float* __restrict__ b_in, float* __restrict__ y0,
    double* __restrict__ STD0, int N)
{
  const int d  = threadIdx.x & 127;
  const int ro = threadIdx.x >> 7;
  float w[10];
  #pragma unroll
  for (int k = 0; k < 10; ++k) w[k] = W_in[k*128 + d];
  const float bi = b_in[d];
  int r0 = blockIdx.x * 128;
  int rend = min(r0 + 128, N);
  double sum = 0.0, sqs = 0.0;
  for (int r = r0 + ro; r < rend; r += 2) {
    const float* xr = x + (size_t)r * 10;
    float acc = bi;
    #pragma unroll
    for (int k = 0; k < 10; ++k) acc += xr[k] * w[k];
    y0[(size_t)r*128 + d] = acc;
    double a = (double)acc;
    sum += a; sqs += a*a;
  }
  int slice = ((blockIdx.x & 3) << 1) | ro;
  atomicAdd(&STD0[slice*512 + d], sum);
  atomicAdd(&STD0[slice*512 + 256 + d], sqs);
}

// ---- BN finalize ----
__global__ void k_bnfin(const double* __restrict__ STDbn,
                        const float* __restrict__ g, const float* __restrict__ beta,
                        float* __restrict__ STFbn, int colofs, double invN)
{
  int col = colofs + threadIdx.x;
  double s = 0.0, q = 0.0;
  #pragma unroll
  for (int sl = 0; sl < 8; ++sl) {
    s += STDbn[sl*512 + col];
    q += STDbn[sl*512 + 256 + col];
  }
  double m = s * invN;
  double var = q * invN - m*m;
  double av = (double)g[col] / sqrt(var + 1e-5);
  STFbn[col] = (float)av;
  STFbn[256 + col] = (float)((double)beta[col] - m*av);
}

// ---- in-place affine + relu on f32 [N,128] ----
__global__ __launch_bounds__(256) void k_affrelu(float* __restrict__ buf,
    const float* __restrict__ STF0, long total4)
{
  long g = (long)blockIdx.x*256 + threadIdx.x;
  if (g >= total4) return;
  int d0 = (int)((g*4) & 127);
  float4 v = ((const float4*)buf)[g];
  float4 av = *(const float4*)(STF0 + d0);
  float4 bv = *(const float4*)(STF0 + 256 + d0);
  v.x = relu_(av.x*v.x + bv.x);
  v.y = relu_(av.y*v.y + bv.y);
  v.z = relu_(av.z*v.z + bv.z);
  v.w = relu_(av.w*v.w + bv.w);
  ((float4*)buf)[g] = v;
}

// ---- column stats ----
template<int C>
__global__ __launch_bounds__(256) void k_colstats(
  const float* __restrict__ p, double* __restrict__ STDr, int N)
{
  int r0 = blockIdx.x * 64;
  int rend = min(r0 + 64, N);
  double s = 0.0, q = 0.0;
  int col, slice;
  if (C == 128) {
    col = threadIdx.x & 127;
    int ro = threadIdx.x >> 7;
    for (int r = r0 + ro; r < rend; r += 2) {
      double v = (double)p[(size_t)r*C + col];
      s += v; q += v*v;
    }
    slice = ((blockIdx.x & 3) << 1) | ro;
  } else {
    col = threadIdx.x;
    for (int r = r0; r < rend; ++r) {
      double v = (double)p[(size_t)r*C + col];
      s += v; q += v*v;
    }
    slice = blockIdx.x & 7;
  }
  atomicAdd(&STDr[slice*512 + col], s);
  atomicAdd(&STDr[slice*512 + 256 + col], q);
}

// ============ GINE aggregation (CSR gather, lane-parallel prefetch) ============
__global__ __launch_bounds__(256) void k_gine_gather(
  const int* __restrict__ off, const int* __restrict__ eid,
  const int* __restrict__ src, const float* __restrict__ eattr,
  const float* __restrict__ We, const float* __restrict__ be,
  const float* __restrict__ L0, float* __restrict__ AG, int N)
{
  int wv = threadIdx.x >> 6, lane = threadIdx.x & 63;
  int t = blockIdx.x*4 + wv;
  if (t >= N) return;
  int o0 = off[t], deg = off[t+1] - o0;
  float2 w2[5];
  #pragma unroll
  for (int i = 0; i < 5; ++i) w2[i] = *(const float2*)(We + i*128 + 2*lane);
  float2 be2 = *(const float2*)(be + 2*lane);
  float2 acc = make_float2(0.f, 0.f);
  for (int base = 0; base < deg; base += 64) {
    int cn = min(64, deg - base);
    int sL = 0; float eaL[5] = {0,0,0,0,0};
    if (lane < cn) {
      int eL = eid[o0 + base + lane];
      sL = src[eL];
      #pragma unroll
      for (int j = 0; j < 5; ++j) eaL[j] = eattr[(size_t)eL*5 + j];
    }
    for (int i = 0; i < cn; ++i) {
      int s_i = __shfl(sL, i);
      float2 xl2 = *(const float2*)(L0 + (size_t)s_i*128 + 2*lane);
      float ex = be2.x, ey = be2.y;
      #pragma unroll
      for (int j = 0; j < 5; ++j) {
        float ea = __shfl(eaL[j], i);
        ex += ea*w2[j].x; ey += ea*w2[j].y;
      }
      acc.x += relu_(xl2.x + ex);
      acc.y += relu_(xl2.y + ey);
    }
  }
  *((float2*)(AG + (size_t)t*128) + lane) = acc;
}

// ============ fused GAT attention per head (registers only, prefetch) ============
#define GCAP 12

#define GAT_EDGE(IDX, POUT, XLOUT) { \
  int e_ = eid[o0 + (IDX)]; int s_ = src[e_]; \
  XLOUT = *(const float2*)(X2 + (size_t)s_*256 + 2*lane); \
  const float* ep_ = eattr + (size_t)e_*5; \
  float fx_ = XLOUT.x + xr2.x, fy_ = XLOUT.y + xr2.y; \
  _Pragma("unroll") \
  for (int j5_ = 0; j5_ < 5; ++j5_) { float ea_ = ep_[j5_]; fx_ += ea_*w2[j5_].x; fy_ += ea_*w2[j5_].y; } \
  fx_ = fx_ > 0.f ? fx_ : 0.2f*fx_; \
  fy_ = fy_ > 0.f ? fy_ : 0.2f*fy_; \
  float pp_ = fx_*at2.x + fy_*at2.y; \
  _Pragma("unroll") \
  for (int mm_ = 1; mm_ < 64; mm_ <<= 1) pp_ += __shfl_xor(pp_, mm_, 64); \
  POUT = pp_; }

__global__ __launch_bounds__(256) void k_gat_attn(
  const int* __restrict__ off, const int* __restrict__ eid,
  const int* __restrict__ src, const float* __restrict__ eattr,
  const float* __restrict__ X2, const float* __restrict__ Weg,
  const float* __restrict__ att, float* __restrict__ AG,
  int N, int h, int first)
{
  int wv = threadIdx.x >> 6, lane = threadIdx.x & 63;
  int t = blockIdx.x*4 + wv;
  if (t >= N) return;
  int o0 = off[t], deg = off[t+1] - o0;
  float2* AGrow = (float2*)(AG + (size_t)t*128) + lane;
  if (deg == 0) { if (first) *AGrow = make_float2(0.f, 0.f); return; }
  int dcol = h*128 + 2*lane;
  float2 xr2 = *(const float2*)(X2 + (size_t)t*256 + 128 + 2*lane);
  float2 at2 = *(const float2*)(att + dcol);
  float2 w2[5];
  #pragma unroll
  for (int i = 0; i < 5; ++i) w2[i] = *(const float2*)(Weg + i*512 + dcol);

  if (deg <= GCAP) {
    int sL = 0; float eaL[5] = {0,0,0,0,0};
    if (lane < deg) {
      int eL = eid[o0 + lane];
      sL = src[eL];
      #pragma unroll
      for (int j = 0; j < 5; ++j) eaL[j] = eattr[(size_t)eL*5 + j];
    }
    float lg[GCAP]; float2 xb[GCAP];
    float mx = -1e30f;
    #pragma unroll
    for (int i = 0; i < GCAP; ++i) {
      if (i < deg) {
        int s_i = __shfl(sL, i);
        float2 xl2 = *(const float2*)(X2 + (size_t)s_i*256 + 2*lane);
        float fx = xl2.x + xr2.x, fy = xl2.y + xr2.y;
        #pragma unroll
        for (int j = 0; j < 5; ++j) {
          float ea = __shfl(eaL[j], i);
          fx += ea*w2[j].x; fy += ea*w2[j].y;
        }
        fx = fx > 0.f ? fx : 0.2f*fx;
        fy = fy > 0.f ? fy : 0.2f*fy;
        float p = fx*at2.x + fy*at2.y;
        #pragma unroll
        for (int m = 1; m < 64; m <<= 1) p += __shfl_xor(p, m, 64);
        lg[i] = p; xb[i] = xl2;
        mx = fmaxf(mx, p);
      }
    }
    float den = 0.f;
    #pragma unroll
    for (int i = 0; i < GCAP; ++i)
      if (i < deg) { lg[i] = expf(lg[i] - mx); den += lg[i]; }
    float sc = 0.25f / den;
    float2 acc = make_float2(0.f, 0.f);
    #pragma unroll
    for (int i = 0; i < GCAP; ++i)
      if (i < deg) { acc.x += lg[i]*xb[i].x; acc.y += lg[i]*xb[i].y; }
    float2 prev = first ? make_float2(0.f,0.f) : *AGrow;
    *AGrow = make_float2(prev.x + sc*acc.x, prev.y + sc*acc.y);
  } else {
    float mx = -1e30f;
    for (int i = 0; i < deg; ++i) { float p; float2 xl2; GAT_EDGE(i, p, xl2); mx = fmaxf(mx, p); (void)xl2; }
    float den = 0.f;
    for (int i = 0; i < deg; ++i) { float p; float2 xl2; GAT_EDGE(i, p, xl2); den += expf(p - mx); (void)xl2; }
    float sc = 0.25f / den;
    float2 acc = make_float2(0.f, 0.f);
    for (int i = 0; i < deg; ++i) {
      float p; float2 xl2; GAT_EDGE(i, p, xl2);
      float al = expf(p - mx);
      acc.x += al*xl2.x; acc.y += al*xl2.y;
    }
    float2 prev = first ? make_float2(0.f,0.f) : *AGrow;
    *AGrow = make_float2(prev.x + sc*acc.x, prev.y + sc*acc.y);
  }
}

// ---- GAT post ----
__global__ __launch_bounds__(128) void k_gat_post(
  float* __restrict__ AG, const float* __restrict__ P1,
  const float* __restrict__ STF, const float* __restrict__ bias_gat,
  const float* __restrict__ skip1, double* __restrict__ STD3, int N)
{
  int d = threadIdx.x;
  float an0 = STF[1024 + d], bn0 = STF[1280 + d];
  float bg = bias_gat[d];
  float s1g = 1.f/(1.f + expf(-skip1[0]));
  float os1 = 1.f - s1g;
  int r0 = blockIdx.x * 256;
  int rend = min(r0 + 256, N);
  double sum = 0.0, sqs = 0.0;
  for (int r = r0; r < rend; ++r) {
    size_t idx = (size_t)r*128 + d;
    float xn = relu_(AG[idx] + bg);
    float l1 = an0*P1[idx] + bn0;
    float p2 = s1g*l1 + os1*xn;
    AG[idx] = p2;
    double dv = (double)p2;
    sum += dv; sqs += dv*dv;
  }
  int slice = blockIdx.x & 7;
  atomicAdd(&STD3[slice*512 + d], sum);
  atomicAdd(&STD3[slice*512 + 256 + d], sqs);
}

// ---- final ----
__global__ __launch_bounds__(256) void k_final(
  float* __restrict__ L0, const float* __restrict__ P1,
  const float* __restrict__ pre2, const float* __restrict__ STF, long total4)
{
  long g = (long)blockIdx.x*256 + threadIdx.x;
  if (g >= total4) return;
  int d0 = (int)((g*4) & 127);
  float4 a0 = *(const float4*)(STF + 1024 + d0);
  float4 b0 = *(const float4*)(STF + 1280 + d0);
  float4 a1 = *(const float4*)(STF + 1536 + d0);
  float4 b1 = *(const float4*)(STF + 1792 + d0);
  float4 v0 = ((const float4*)L0)[g];
  float4 v1 = ((const float4*)P1)[g];
  float4 v2 = ((const float4*)pre2)[g];
  float4 o;
  const float k3 = 1.f/3.f;
  o.x = (v0.x + (a0.x*v1.x + b0.x) + (a1.x*v2.x + b1.x)) * k3;
  o.y = (v0.y + (a0.y*v1.y + b0.y) + (a1.y*v2.y + b1.y)) * k3;
  o.z = (v0.z + (a0.z*v1.z + b0.z) + (a1.z*v2.z + b1.z)) * k3;
  o.w = (v0.w + (a0.w*v1.w + b0.w) + (a1.w*v2.w + b1.w)) * k3;
  ((float4*)L0)[g] = o;
}

// ---------------- host launch ----------------
extern "C" void kernel_launch(void* const* d_in, const int* in_sizes, int n_in,
                              void* d_out, int out_size, void* d_ws, size_t ws_size,
                              hipStream_t stream)
{
  const float* x       = (const float*)d_in[0];
  const int*   eidx    = (const int*)  d_in[1];
  const float* eattr   = (const float*)d_in[2];
  const float* W_in    = (const float*)d_in[4];
  const float* b_in    = (const float*)d_in[5];
  const float* g_in    = (const float*)d_in[6];
  const float* beta_in = (const float*)d_in[7];
  const float* We      = (const float*)d_in[8];
  const float* be      = (const float*)d_in[9];
  const float* W1      = (const float*)d_in[10];
  const float* b1      = (const float*)d_in[11];
  const float* g1      = (const float*)d_in[12];
  const float* beta1   = (const float*)d_in[13];
  const float* W2      = (const float*)d_in[14];
  const float* b2      = (const float*)d_in[15];
  const float* skip0   = (const float*)d_in[16];
  const float* skip1   = (const float*)d_in[17];
  const float* g_n0    = (const float*)d_in[18];
  const float* b_n0    = (const float*)d_in[19];
  const float* g_n1    = (const float*)d_in[20];
  const float* b_n1    = (const float*)d_in[21];
  const float* Wl      = (const float*)d_in[22];
  const float* bl      = (const float*)d_in[23];
  const float* Wr      = (const float*)d_in[24];
  const float* br      = (const float*)d_in[25];
  const float* att     = (const float*)d_in[26];
  const float* Weg     = (const float*)d_in[27];
  const float* bias_g  = (const float*)d_in[28];

  const int N = in_sizes[0] / 10;
  const int E = in_sizes[1] / 2;
  const int* srcv = eidx;
  const int* dstv = eidx + E;

  float* L0 = (float*)d_out;                 // layer0 lives in d_out; finalized in place

  // ---- workspace layout (~207 MB + ~0.8 MB packs) ----
  char* wsb = (char*)d_ws;
  const size_t szN128 = (size_t)N*128*4;
  size_t oSTD = 0;                           // 16384 doubles
  size_t oSTF = oSTD + 131072;
  size_t oAG  = oSTF + 8192;                 // f32 [N,128]
  size_t oP1  = oAG + szN128;                // f32 [N,128]
  size_t oX2  = oP1 + szN128;                // f32 [N,256]
  size_t oCNT = oX2 + 2*szN128;              // int [N]
  size_t oFIL = oCNT + (size_t)N*4;
  size_t oOFF = oFIL + (size_t)N*4;          // int [N+1]
  size_t oEID = oOFF + (size_t)(N+1)*4;      // int [E]
  size_t oBS  = oEID + (size_t)E*4;          // int [256]
  size_t oBOF = oBS + 1024;                  // int [256]
  size_t oBP1 = oBOF + 1024;                 // y1 pack: 8192 uint4 = 128 KB
  size_t oBP2 = oBP1 + 8192*16;              // W2 pack: 8192 uint4
  size_t oBPG = oBP2 + 8192*16;              // gat packs: 4*8192 uint4
  size_t oBPB = oBPG + 4*8192*16;            // gat bias: 1024 floats

  double* STD = (double*)(wsb + oSTD);
  float*  STF = (float*) (wsb + oSTF);
  float*  AG  = (float*) (wsb + oAG);
  float*  P1  = (float*) (wsb + oP1);
  float*  X2  = (float*) (wsb + oX2);
  int*    CNT = (int*)   (wsb + oCNT);
  int*    FIL = (int*)   (wsb + oFIL);
  int*    OFF = (int*)   (wsb + oOFF);
  int*    EID = (int*)   (wsb + oEID);
  int*    BS  = (int*)   (wsb + oBS);
  int*    BOF = (int*)   (wsb + oBOF);
  uint4*  BP1 = (uint4*) (wsb + oBP1);
  uint4*  BP2 = (uint4*) (wsb + oBP2);
  uint4*  BPG = (uint4*) (wsb + oBPG);
  float*  BPB = (float*) (wsb + oBPB);

  const double invN = 1.0 / (double)N;
  const int nb = (N + 63)/64;
  const int nscan = (N + 1023)/1024;

  hipMemsetAsync(STD, 0, 131072, stream);
  hipMemsetAsync(CNT, 0, (size_t)N*4, stream);
  hipMemsetAsync(FIL, 0, (size_t)N*4, stream);

  // ---- weight packs (tiny, once) ----
  k_packB<<<16*4, 64, 0, stream>>>(W1, 256, 0, 0, 4, 16, BP1);
  k_packB<<<8*8,  64, 0, stream>>>(W2, 128, 0, 0, 8, 8,  BP2);
  for (int h = 0; h < 4; ++h) {
    k_packB<<<8*4, 64, 0, stream>>>(Wl, 512, h*128, 0, 4, 16, BPG + (size_t)h*8192);
    k_packB<<<8*4, 64, 0, stream>>>(Wr, 512, h*128, 8, 4, 16, BPG + (size_t)h*8192);
  }
  k_packbias<<<4, 256, 0, stream>>>(bl, br, BPB);

  // ---- CSR build (dst-sorted) ----
  k_hist <<<(E + 255)/256, 256, 0, stream>>>(dstv, CNT, E);
  k_scan1<<<nscan, 256, 0, stream>>>(CNT, OFF, BS, N);
  k_scan2<<<1, 64, 0, stream>>>(BS, BOF, nscan);
  k_scan3<<<nscan, 256, 0, stream>>>(OFF, BOF, N);
  k_fill <<<(E + 255)/256, 256, 0, stream>>>(dstv, OFF, FIL, EID, E);

  // ---- input projection + BN + relu -> L0 ----
  k_inproj<<<(N + 127)/128, 256, 0, stream>>>(x, W_in, b_in, L0, STD_BN(STD,0), N);
  k_bnfin<<<1, 128, 0, stream>>>(STD_BN(STD,0), g_in, beta_in, STF + 0, 0, invN);
  {
    long t4 = (long)N*32;
    k_affrelu<<<(unsigned)((t4 + 255)/256), 256, 0, stream>>>(L0, STF + 0, t4);
  }

  // ---- GINE aggregation (CSR gather) ----
  k_gine_gather<<<(N + 3)/4, 256, 0, stream>>>(OFF, EID, srcv, eattr, We, be, L0, AG, N);

  // ---- GINE MLP (MFMA split-f16) ----
  k_mfma<0,0,128,256><<<nb, 256, 0, stream>>>(L0, AG, STF, 0, BP1, b1, nullptr, nullptr, X2, N);
  k_colstats<256><<<nb, 256, 0, stream>>>(X2, STD_BN(STD,1), N);
  k_bnfin<<<1, 256, 0, stream>>>(STD_BN(STD,1), g1, beta1, STF + 512, 0, invN);
  k_mfma<1,1,256,128><<<nb, 256, 0, stream>>>(X2, nullptr, STF, 512, BP2, b2, L0, skip0, P1, N);
  k_colstats<128><<<nb, 256, 0, stream>>>(P1, STD_BN(STD,2), N);
  k_bnfin<<<1, 128, 0, stream>>>(STD_BN(STD,2), g_n0, b_n0, STF + 1024, 0, invN);

  // ---- GAT head-by-head: MFMA transform (xl|xr) + fused attention ----
  for (int h = 0; h < 4; ++h) {
    k_mfma<2,0,128,256><<<nb, 256, 0, stream>>>(P1, nullptr, STF, 1024,
                                                BPG + (size_t)h*8192, BPB + h*256,
                                                nullptr, nullptr, X2, N);
    k_gat_attn<<<(N + 3)/4, 256, 0, stream>>>(OFF, EID, srcv, eattr, X2, Weg, att,
                                              AG, N, h, (h == 0) ? 1 : 0);
  }

  // ---- post + BN n1 + final ----
  k_gat_post<<<(N + 255)/256, 128, 0, stream>>>(AG, P1, STF, bias_g, skip1, STD_BN(STD,3), N);
  k_bnfin<<<1, 128, 0, stream>>>(STD_BN(STD,3), g_n1, b_n1, STF + 1536, 0, invN);
  {
    long t4 = (long)N*32;
    k_final<<<(unsigned)((t4 + 255)/256), 256, 0, stream>>>(L0, P1, AG, STF, t4);
  }
  (void)n_in; (void)out_size; (void)ws_size;
}

// Round 8
// 1193.846 us; speedup vs baseline: 2.2765x; 1.0553x over previous
//
#include <hip/hip_runtime.h>
#include <stdint.h>

// ---------------- helpers ----------------
__device__ __forceinline__ float relu_(float v){ return v > 0.f ? v : 0.f; }

typedef _Float16 f16;
typedef f16 f16x8 __attribute__((ext_vector_type(8)));
typedef float f32x4 __attribute__((ext_vector_type(4)));

__device__ __forceinline__ f16x8 u2h(uint4 u){ union{uint4 u; f16x8 h;} c; c.u=u; return c.h; }

// ---------------- STD (f64 stats): 4 BN regions x [8 slices][2][256] doubles ----
#define STD_BN(p, idx) ((p) + (size_t)(idx) * 4096)
// STF (f32): a/b pairs: in@0, mlp@512, n0@1024, n1@1536 (a base+0..255, b base+256..511)

// ============ CSR build ============
__global__ __launch_bounds__(256) void k_hist(const int* __restrict__ dst,
                                              int* __restrict__ cnt, int E)
{
  int e = blockIdx.x*256 + threadIdx.x;
  if (e < E) atomicAdd(&cnt[dst[e]], 1);
}

__global__ __launch_bounds__(256) void k_scan1(const int* __restrict__ cnt,
    int* __restrict__ off, int* __restrict__ bsum, int N)
{
  __shared__ int part[256];
  int tid = threadIdx.x;
  int base = blockIdx.x*1024 + tid*4;
  int v[4]; int s = 0;
  #pragma unroll
  for (int j = 0; j < 4; ++j) { v[j] = (base + j < N) ? cnt[base + j] : 0; s += v[j]; }
  part[tid] = s;
  __syncthreads();
  #pragma unroll
  for (int d = 1; d < 256; d <<= 1) {
    int tv = (tid >= d) ? part[tid - d] : 0;
    __syncthreads();
    part[tid] += tv;
    __syncthreads();
  }
  int run = part[tid] - s;
  #pragma unroll
  for (int j = 0; j < 4; ++j) {
    run += v[j];
    if (base + j < N) off[base + j + 1] = run;
  }
  if (tid == 255) bsum[blockIdx.x] = part[255];
}

__global__ void k_scan2(const int* __restrict__ bsum, int* __restrict__ bofs, int nb)
{
  if (threadIdx.x == 0) {
    int run = 0;
    for (int b = 0; b < nb; ++b) { bofs[b] = run; run += bsum[b]; }
  }
}

__global__ __launch_bounds__(256) void k_scan3(int* __restrict__ off,
    const int* __restrict__ bofs, int N)
{
  int tid = threadIdx.x;
  int base = blockIdx.x*1024 + tid*4;
  int add = bofs[blockIdx.x];
  #pragma unroll
  for (int j = 0; j < 4; ++j)
    if (base + j < N) off[base + j + 1] += add;
  if (blockIdx.x == 0 && tid == 0) off[0] = 0;
}

__global__ __launch_bounds__(256) void k_fill(const int* __restrict__ dst,
    const int* __restrict__ off, int* __restrict__ fill,
    int* __restrict__ eid, int E)
{
  int e = blockIdx.x*256 + threadIdx.x;
  if (e >= E) return;
  int t = dst[e];
  int pos = off[t] + atomicAdd(&fill[t], 1);
  eid[pos] = e;
}

// ============ weight pack: fragment-ordered f16 hi/lo ============
// Bpk element idx = ((ks*nctFull + ct0+ctl)*64 + lane)*2 + {0:hi,1:lo}
__global__ __launch_bounds__(64) void k_packB(
  const float* __restrict__ W, int ldw, int cb,
  int ct0, int nks, int nctFull, uint4* __restrict__ Bpk)
{
  int ks  = blockIdx.x % nks;
  int ctl = blockIdx.x / nks;
  int lane = threadIdx.x;
  int col = cb + ctl*16 + (lane & 15);
  int kbase = ks*32 + (lane >> 4)*8;
  f16x8 hi, lo;
  #pragma unroll
  for (int i = 0; i < 8; ++i) {
    float w = W[(size_t)(kbase + i)*ldw + col];
    f16 h = (f16)w;
    hi[i] = h;
    lo[i] = (f16)(w - (float)h);
  }
  union{f16x8 h; uint4 u;} ch, cl; ch.h = hi; cl.h = lo;
  size_t idx = ((size_t)(ks*nctFull + ct0 + ctl)*64 + lane)*2;
  Bpk[idx] = ch.u;
  Bpk[idx + 1] = cl.u;
}

// GAT bias pack
__global__ void k_packbias(const float* __restrict__ bl, const float* __restrict__ br,
                           float* __restrict__ bp)
{
  int c = threadIdx.x, h = blockIdx.x;
  bp[h*256 + c] = (c < 128) ? bl[h*128 + c] : br[h*128 + (c - 128)];
}

// ============ MFMA GEMM: no LDS, no barriers; A-frags direct from global ============
// PREP 0: A = A0 + A1           (gine1,  K=128)
// PREP 1: A = relu(a*A0 + c)    (gine2,  K=256, stfofs=512)
// PREP 2: A = a*A0 + c          (gat,    K=128, stfofs=1024)
// EPI  0: OUT = acc + biasp[col]
// EPI  1: OUT = s0*l0 + (1-s0)*relu(acc + biasp[col])   (NT=128)
template<int PREP, int EPI, int K, int NT>
__global__ __launch_bounds__(256) void k_mfma(
  const float* __restrict__ A0, const float* __restrict__ A1,
  const float* __restrict__ STF, int stfofs,
  const uint4* __restrict__ Bpk, const float* __restrict__ biasp,
  const float* __restrict__ l0, const float* __restrict__ sk,
  float* __restrict__ OUT, int N)
{
  constexpr int NCT = NT/16;
  constexpr int KS = K/32;
  const int tid = threadIdx.x;
  const int lane = tid & 63, wv = tid >> 6;
  const int fr = lane & 15, fg = lane >> 4;
  const int row0 = blockIdx.x * 64;
  const int arowi = row0 + wv*16 + fr;          // A-fragment row (M index)
  const bool avalid = arowi < N;
  const float* arow  = A0 + (size_t)(avalid ? arowi : 0) * K;
  const float* arow1 = (PREP == 0) ? (A1 + (size_t)(avalid ? arowi : 0) * K) : (const float*)nullptr;

  f32x4 acc[NCT];
  #pragma unroll
  for (int ct = 0; ct < NCT; ++ct) acc[ct] = (f32x4){0.f, 0.f, 0.f, 0.f};

  // A-fragment load + PREP (8 floats at k = ks*32 + fg*8)
  auto loadA = [&](int ks, float4& va, float4& vb) {
    int k = ks*32 + fg*8;
    float4 x = *(const float4*)(arow + k);
    float4 y = *(const float4*)(arow + k + 4);
    if (PREP == 0) {
      float4 g0 = *(const float4*)(arow1 + k);
      float4 g1 = *(const float4*)(arow1 + k + 4);
      x.x += g0.x; x.y += g0.y; x.z += g0.z; x.w += g0.w;
      y.x += g1.x; y.y += g1.y; y.z += g1.z; y.w += g1.w;
    } else {
      float4 a0 = *(const float4*)(STF + stfofs + k);
      float4 a1 = *(const float4*)(STF + stfofs + k + 4);
      float4 c0 = *(const float4*)(STF + stfofs + 256 + k);
      float4 c1 = *(const float4*)(STF + stfofs + 256 + k + 4);
      x.x = a0.x*x.x + c0.x; x.y = a0.y*x.y + c0.y;
      x.z = a0.z*x.z + c0.z; x.w = a0.w*x.w + c0.w;
      y.x = a1.x*y.x + c1.x; y.y = a1.y*y.y + c1.y;
      y.z = a1.z*y.z + c1.z; y.w = a1.w*y.w + c1.w;
      if (PREP == 1) {
        x.x = relu_(x.x); x.y = relu_(x.y); x.z = relu_(x.z); x.w = relu_(x.w);
        y.x = relu_(y.x); y.y = relu_(y.y); y.z = relu_(y.z); y.w = relu_(y.w);
      }
    }
    if (!avalid) { x = make_float4(0,0,0,0); y = make_float4(0,0,0,0); }
    va = x; vb = y;
  };

  float4 cva, cvb, nva, nvb;
  loadA(0, cva, cvb);
  #pragma unroll
  for (int ks = 0; ks < KS; ++ks) {
    if (ks + 1 < KS) loadA(ks + 1, nva, nvb);      // register double-buffer
    float av[8] = {cva.x,cva.y,cva.z,cva.w,cvb.x,cvb.y,cvb.z,cvb.w};
    f16x8 ah, al;
    #pragma unroll
    for (int i = 0; i < 8; ++i) {
      f16 h = (f16)av[i];
      ah[i] = h;
      al[i] = (f16)(av[i] - (float)h);
    }
    const uint4* bp = Bpk + ((size_t)ks*NCT*64 + lane)*2;
    #pragma unroll
    for (int ct = 0; ct < NCT; ++ct) {
      f16x8 bh = u2h(bp[ct*128]);
      f16x8 bl = u2h(bp[ct*128 + 1]);
      acc[ct] = __builtin_amdgcn_mfma_f32_16x16x32_f16(ah, bh, acc[ct], 0, 0, 0);
      acc[ct] = __builtin_amdgcn_mfma_f32_16x16x32_f16(ah, bl, acc[ct], 0, 0, 0);
      acc[ct] = __builtin_amdgcn_mfma_f32_16x16x32_f16(al, bh, acc[ct], 0, 0, 0);
    }
    cva = nva; cvb = nvb;
  }

  // epilogue: D[col=lane&15, row=(lane>>4)*4+rr] per 16x16 tile (verified layout)
  float s0g = 0.f, os0 = 0.f;
  if (EPI == 1) { s0g = 1.f/(1.f + expf(-sk[0])); os0 = 1.f - s0g; }
  #pragma unroll
  for (int ct = 0; ct < NCT; ++ct) {
    int col = ct*16 + fr;
    float bv = biasp[col];
    #pragma unroll
    for (int rr = 0; rr < 4; ++rr) {
      int row = row0 + wv*16 + fg*4 + rr;
      if (row < N) {
        float v = acc[ct][rr] + bv;
        if (EPI == 1) v = s0g*l0[(size_t)row*128 + col] + os0*relu_(v);
        OUT[(size_t)row*NT + col] = v;
      }
    }
  }
}

// ============ input projection (256 threads: 2-row parallel) ============
__global__ __launch_bounds__(256) void k_inproj(
    const float* __restrict__ x, const float* __restrict__ W_in,
    const float* __restrict__ b_in, float* __restrict__ y0,
    double* __restrict__ STD0, int N)
{
  const int d  = threadIdx.x & 127;
  const int ro = threadIdx.x >> 7;
  float w[10];
  #pragma unroll
  for (int k = 0; k < 10; ++k) w[k] = W_in[k*128 + d];
  const float bi = b_in[d];
  int r0 = blockIdx.x * 128;
  int rend = min(r0 + 128, N);
  double sum = 0.0, sqs = 0.0;
  for (int r = r0 + ro; r < rend; r += 2) {
    const float* xr = x + (size_t)r * 10;
    float acc = bi;
    #pragma unroll
    for (int k = 0; k < 10; ++k) acc += xr[k] * w[k];
    y0[(size_t)r*128 + d] = acc;
    double a = (double)acc;
    sum += a; sqs += a*a;
  }
  int slice = ((blockIdx.x & 3) << 1) | ro;
  atomicAdd(&STD0[slice*512 + d], sum);
  atomicAdd(&STD0[slice*512 + 256 + d], sqs);
}

// ---- BN finalize ----
__global__ void k_bnfin(const double* __restrict__ STDbn,
                        const float* __restrict__ g, const float* __restrict__ beta,
                        float* __restrict__ STFbn, int colofs, double invN)
{
  int col = colofs + threadIdx.x;
  double s = 0.0, q = 0.0;
  #pragma unroll
  for (int sl = 0; sl < 8; ++sl) {
    s += STDbn[sl*512 + col];
    q += STDbn[sl*512 + 256 + col];
  }
  double m = s * invN;
  double var = q * invN - m*m;
  double av = (double)g[col] / sqrt(var + 1e-5);
  STFbn[col] = (float)av;
  STFbn[256 + col] = (float)((double)beta[col] - m*av);
}

// ---- in-place affine + relu on f32 [N,128] ----
__global__ __launch_bounds__(256) void k_affrelu(float* __restrict__ buf,
    const float* __restrict__ STF0, long total4)
{
  long g = (long)blockIdx.x*256 + threadIdx.x;
  if (g >= total4) return;
  int d0 = (int)((g*4) & 127);
  float4 v = ((const float4*)buf)[g];
  float4 av = *(const float4*)(STF0 + d0);
  float4 bv = *(const float4*)(STF0 + 256 + d0);
  v.x = relu_(av.x*v.x + bv.x);
  v.y = relu_(av.y*v.y + bv.y);
  v.z = relu_(av.z*v.z + bv.z);
  v.w = relu_(av.w*v.w + bv.w);
  ((float4*)buf)[g] = v;
}

// ---- column stats ----
template<int C>
__global__ __launch_bounds__(256) void k_colstats(
  const float* __restrict__ p, double* __restrict__ STDr, int N)
{
  int r0 = blockIdx.x * 64;
  int rend = min(r0 + 64, N);
  double s = 0.0, q = 0.0;
  int col, slice;
  if (C == 128) {
    col = threadIdx.x & 127;
    int ro = threadIdx.x >> 7;
    for (int r = r0 + ro; r < rend; r += 2) {
      double v = (double)p[(size_t)r*C + col];
      s += v; q += v*v;
    }
    slice = ((blockIdx.x & 3) << 1) | ro;
  } else {
    col = threadIdx.x;
    for (int r = r0; r < rend; ++r) {
      double v = (double)p[(size_t)r*C + col];
      s += v; q += v*v;
    }
    slice = blockIdx.x & 7;
  }
  atomicAdd(&STDr[slice*512 + col], s);
  atomicAdd(&STDr[slice*512 + 256 + col], q);
}

// ============ GINE aggregation (CSR gather, lane-parallel prefetch) ============
__global__ __launch_bounds__(256) void k_gine_gather(
  const int* __restrict__ off, const int* __restrict__ eid,
  const int* __restrict__ src, const float* __restrict__ eattr,
  const float* __restrict__ We, const float* __restrict__ be,
  const float* __restrict__ L0, float* __restrict__ AG, int N)
{
  int wv = threadIdx.x >> 6, lane = threadIdx.x & 63;
  int t = blockIdx.x*4 + wv;
  if (t >= N) return;
  int o0 = off[t], deg = off[t+1] - o0;
  float2 w2[5];
  #pragma unroll
  for (int i = 0; i < 5; ++i) w2[i] = *(const float2*)(We + i*128 + 2*lane);
  float2 be2 = *(const float2*)(be + 2*lane);
  float2 acc = make_float2(0.f, 0.f);
  for (int base = 0; base < deg; base += 64) {
    int cn = min(64, deg - base);
    int sL = 0; float eaL[5] = {0,0,0,0,0};
    if (lane < cn) {
      int eL = eid[o0 + base + lane];
      sL = src[eL];
      #pragma unroll
      for (int j = 0; j < 5; ++j) eaL[j] = eattr[(size_t)eL*5 + j];
    }
    for (int i = 0; i < cn; ++i) {
      int s_i = __shfl(sL, i);
      float2 xl2 = *(const float2*)(L0 + (size_t)s_i*128 + 2*lane);
      float ex = be2.x, ey = be2.y;
      #pragma unroll
      for (int j = 0; j < 5; ++j) {
        float ea = __shfl(eaL[j], i);
        ex += ea*w2[j].x; ey += ea*w2[j].y;
      }
      acc.x += relu_(xl2.x + ex);
      acc.y += relu_(xl2.y + ey);
    }
  }
  *((float2*)(AG + (size_t)t*128) + lane) = acc;
}

// ============ fused GAT attention per head (registers only, prefetch) ============
#define GCAP 12

#define GAT_EDGE(IDX, POUT, XLOUT) { \
  int e_ = eid[o0 + (IDX)]; int s_ = src[e_]; \
  XLOUT = *(const float2*)(X2 + (size_t)s_*256 + 2*lane); \
  const float* ep_ = eattr + (size_t)e_*5; \
  float fx_ = XLOUT.x + xr2.x, fy_ = XLOUT.y + xr2.y; \
  _Pragma("unroll") \
  for (int j5_ = 0; j5_ < 5; ++j5_) { float ea_ = ep_[j5_]; fx_ += ea_*w2[j5_].x; fy_ += ea_*w2[j5_].y; } \
  fx_ = fx_ > 0.f ? fx_ : 0.2f*fx_; \
  fy_ = fy_ > 0.f ? fy_ : 0.2f*fy_; \
  float pp_ = fx_*at2.x + fy_*at2.y; \
  _Pragma("unroll") \
  for (int mm_ = 1; mm_ < 64; mm_ <<= 1) pp_ += __shfl_xor(pp_, mm_, 64); \
  POUT = pp_; }

__global__ __launch_bounds__(256) void k_gat_attn(
  const int* __restrict__ off, const int* __restrict__ eid,
  const int* __restrict__ src, const float* __restrict__ eattr,
  const float* __restrict__ X2, const float* __restrict__ Weg,
  const float* __restrict__ att, float* __restrict__ AG,
  int N, int h, int first)
{
  int wv = threadIdx.x >> 6, lane = threadIdx.x & 63;
  int t = blockIdx.x*4 + wv;
  if (t >= N) return;
  int o0 = off[t], deg = off[t+1] - o0;
  float2* AGrow = (float2*)(AG + (size_t)t*128) + lane;
  if (deg == 0) { if (first) *AGrow = make_float2(0.f, 0.f); return; }
  int dcol = h*128 + 2*lane;
  float2 xr2 = *(const float2*)(X2 + (size_t)t*256 + 128 + 2*lane);
  float2 at2 = *(const float2*)(att + dcol);
  float2 w2[5];
  #pragma unroll
  for (int i = 0; i < 5; ++i) w2[i] = *(const float2*)(Weg + i*512 + dcol);

  if (deg <= GCAP) {
    int sL = 0; float eaL[5] = {0,0,0,0,0};
    if (lane < deg) {
      int eL = eid[o0 + lane];
      sL = src[eL];
      #pragma unroll
      for (int j = 0; j < 5; ++j) eaL[j] = eattr[(size_t)eL*5 + j];
    }
    float lg[GCAP]; float2 xb[GCAP];
    float mx = -1e30f;
    #pragma unroll
    for (int i = 0; i < GCAP; ++i) {
      if (i < deg) {
        int s_i = __shfl(sL, i);
        float2 xl2 = *(const float2*)(X2 + (size_t)s_i*256 + 2*lane);
        float fx = xl2.x + xr2.x, fy = xl2.y + xr2.y;
        #pragma unroll
        for (int j = 0; j < 5; ++j) {
          float ea = __shfl(eaL[j], i);
          fx += ea*w2[j].x; fy += ea*w2[j].y;
        }
        fx = fx > 0.f ? fx : 0.2f*fx;
        fy = fy > 0.f ? fy : 0.2f*fy;
        float p = fx*at2.x + fy*at2.y;
        #pragma unroll
        for (int m = 1; m < 64; m <<= 1) p += __shfl_xor(p, m, 64);
        lg[i] = p; xb[i] = xl2;
        mx = fmaxf(mx, p);
      }
    }
    float den = 0.f;
    #pragma unroll
    for (int i = 0; i < GCAP; ++i)
      if (i < deg) { lg[i] = expf(lg[i] - mx); den += lg[i]; }
    float sc = 0.25f / den;
    float2 acc = make_float2(0.f, 0.f);
    #pragma unroll
    for (int i = 0; i < GCAP; ++i)
      if (i < deg) { acc.x += lg[i]*xb[i].x; acc.y += lg[i]*xb[i].y; }
    float2 prev = first ? make_float2(0.f,0.f) : *AGrow;
    *AGrow = make_float2(prev.x + sc*acc.x, prev.y + sc*acc.y);
  } else {
    float mx = -1e30f;
    for (int i = 0; i < deg; ++i) { float p; float2 xl2; GAT_EDGE(i, p, xl2); mx = fmaxf(mx, p); (void)xl2; }
    float den = 0.f;
    for (int i = 0; i < deg; ++i) { float p; float2 xl2; GAT_EDGE(i, p, xl2); den += expf(p - mx); (void)xl2; }
    float sc = 0.25f / den;
    float2 acc = make_float2(0.f, 0.f);
    for (int i = 0; i < deg; ++i) {
      float p; float2 xl2; GAT_EDGE(i, p, xl2);
      float al = expf(p - mx);
      acc.x += al*xl2.x; acc.y += al*xl2.y;
    }
    float2 prev = first ? make_float2(0.f,0.f) : *AGrow;
    *AGrow = make_float2(prev.x + sc*acc.x, prev.y + sc*acc.y);
  }
}

// ---- GAT post ----
__global__ __launch_bounds__(128) void k_gat_post(
  float* __restrict__ AG, const float* __restrict__ P1,
  const float* __restrict__ STF, const float* __restrict__ bias_gat,
  const float* __restrict__ skip1, double* __restrict__ STD3, int N)
{
  int d = threadIdx.x;
  float an0 = STF[1024 + d], bn0 = STF[1280 + d];
  float bg = bias_gat[d];
  float s1g = 1.f/(1.f + expf(-skip1[0]));
  float os1 = 1.f - s1g;
  int r0 = blockIdx.x * 256;
  int rend = min(r0 + 256, N);
  double sum = 0.0, sqs = 0.0;
  for (int r = r0; r < rend; ++r) {
    size_t idx = (size_t)r*128 + d;
    float xn = relu_(AG[idx] + bg);
    float l1 = an0*P1[idx] + bn0;
    float p2 = s1g*l1 + os1*xn;
    AG[idx] = p2;
    double dv = (double)p2;
    sum += dv; sqs += dv*dv;
  }
  int slice = blockIdx.x & 7;
  atomicAdd(&STD3[slice*512 + d], sum);
  atomicAdd(&STD3[slice*512 + 256 + d], sqs);
}

// ---- final ----
__global__ __launch_bounds__(256) void k_final(
  float* __restrict__ L0, const float* __restrict__ P1,
  const float* __restrict__ pre2, const float* __restrict__ STF, long total4)
{
  long g = (long)blockIdx.x*256 + threadIdx.x;
  if (g >= total4) return;
  int d0 = (int)((g*4) & 127);
  float4 a0 = *(const float4*)(STF + 1024 + d0);
  float4 b0 = *(const float4*)(STF + 1280 + d0);
  float4 a1 = *(const float4*)(STF + 1536 + d0);
  float4 b1 = *(const float4*)(STF + 1792 + d0);
  float4 v0 = ((const float4*)L0)[g];
  float4 v1 = ((const float4*)P1)[g];
  float4 v2 = ((const float4*)pre2)[g];
  float4 o;
  const float k3 = 1.f/3.f;
  o.x = (v0.x + (a0.x*v1.x + b0.x) + (a1.x*v2.x + b1.x)) * k3;
  o.y = (v0.y + (a0.y*v1.y + b0.y) + (a1.y*v2.y + b1.y)) * k3;
  o.z = (v0.z + (a0.z*v1.z + b0.z) + (a1.z*v2.z + b1.z)) * k3;
  o.w = (v0.w + (a0.w*v1.w + b0.w) + (a1.w*v2.w + b1.w)) * k3;
  ((float4*)L0)[g] = o;
}

// ---------------- host launch ----------------
extern "C" void kernel_launch(void* const* d_in, const int* in_sizes, int n_in,
                              void* d_out, int out_size, void* d_ws, size_t ws_size,
                              hipStream_t stream)
{
  const float* x       = (const float*)d_in[0];
  const int*   eidx    = (const int*)  d_in[1];
  const float* eattr   = (const float*)d_in[2];
  const float* W_in    = (const float*)d_in[4];
  const float* b_in    = (const float*)d_in[5];
  const float* g_in    = (const float*)d_in[6];
  const float* beta_in = (const float*)d_in[7];
  const float* We      = (const float*)d_in[8];
  const float* be      = (const float*)d_in[9];
  const float* W1      = (const float*)d_in[10];
  const float* b1      = (const float*)d_in[11];
  const float* g1      = (const float*)d_in[12];
  const float* beta1   = (const float*)d_in[13];
  const float* W2      = (const float*)d_in[14];
  const float* b2      = (const float*)d_in[15];
  const float* skip0   = (const float*)d_in[16];
  const float* skip1   = (const float*)d_in[17];
  const float* g_n0    = (const float*)d_in[18];
  const float* b_n0    = (const float*)d_in[19];
  const float* g_n1    = (const float*)d_in[20];
  const float* b_n1    = (const float*)d_in[21];
  const float* Wl      = (const float*)d_in[22];
  const float* bl      = (const float*)d_in[23];
  const float* Wr      = (const float*)d_in[24];
  const float* br      = (const float*)d_in[25];
  const float* att     = (const float*)d_in[26];
  const float* Weg     = (const float*)d_in[27];
  const float* bias_g  = (const float*)d_in[28];

  const int N = in_sizes[0] / 10;
  const int E = in_sizes[1] / 2;
  const int* srcv = eidx;
  const int* dstv = eidx + E;

  float* L0 = (float*)d_out;                 // layer0 lives in d_out; finalized in place

  // ---- workspace layout (~207 MB + ~0.8 MB packs) ----
  char* wsb = (char*)d_ws;
  const size_t szN128 = (size_t)N*128*4;
  size_t oSTD = 0;                           // 16384 doubles
  size_t oSTF = oSTD + 131072;
  size_t oAG  = oSTF + 8192;                 // f32 [N,128]
  size_t oP1  = oAG + szN128;                // f32 [N,128]
  size_t oX2  = oP1 + szN128;                // f32 [N,256]
  size_t oCNT = oX2 + 2*szN128;              // int [N]
  size_t oFIL = oCNT + (size_t)N*4;
  size_t oOFF = oFIL + (size_t)N*4;          // int [N+1]
  size_t oEID = oOFF + (size_t)(N+1)*4;      // int [E]
  size_t oBS  = oEID + (size_t)E*4;          // int [256]
  size_t oBOF = oBS + 1024;                  // int [256]
  size_t oBP1 = oBOF + 1024;                 // y1 pack: 8192 uint4 = 128 KB
  size_t oBP2 = oBP1 + 8192*16;              // W2 pack
  size_t oBPG = oBP2 + 8192*16;              // gat packs: 4x
  size_t oBPB = oBPG + 4*8192*16;            // gat bias

  double* STD = (double*)(wsb + oSTD);
  float*  STF = (float*) (wsb + oSTF);
  float*  AG  = (float*) (wsb + oAG);
  float*  P1  = (float*) (wsb + oP1);
  float*  X2  = (float*) (wsb + oX2);
  int*    CNT = (int*)   (wsb + oCNT);
  int*    FIL = (int*)   (wsb + oFIL);
  int*    OFF = (int*)   (wsb + oOFF);
  int*    EID = (int*)   (wsb + oEID);
  int*    BS  = (int*)   (wsb + oBS);
  int*    BOF = (int*)   (wsb + oBOF);
  uint4*  BP1 = (uint4*) (wsb + oBP1);
  uint4*  BP2 = (uint4*) (wsb + oBP2);
  uint4*  BPG = (uint4*) (wsb + oBPG);
  float*  BPB = (float*) (wsb + oBPB);

  const double invN = 1.0 / (double)N;
  const int nb = (N + 63)/64;
  const int nscan = (N + 1023)/1024;

  hipMemsetAsync(STD, 0, 131072, stream);
  hipMemsetAsync(CNT, 0, (size_t)N*4, stream);
  hipMemsetAsync(FIL, 0, (size_t)N*4, stream);

  // ---- weight packs (tiny, once) ----
  k_packB<<<16*4, 64, 0, stream>>>(W1, 256, 0, 0, 4, 16, BP1);
  k_packB<<<8*8,  64, 0, stream>>>(W2, 128, 0, 0, 8, 8,  BP2);
  for (int h = 0; h < 4; ++h) {
    k_packB<<<8*4, 64, 0, stream>>>(Wl, 512, h*128, 0, 4, 16, BPG + (size_t)h*8192);
    k_packB<<<8*4, 64, 0, stream>>>(Wr, 512, h*128, 8, 4, 16, BPG + (size_t)h*8192);
  }
  k_packbias<<<4, 256, 0, stream>>>(bl, br, BPB);

  // ---- CSR build (dst-sorted) ----
  k_hist <<<(E + 255)/256, 256, 0, stream>>>(dstv, CNT, E);
  k_scan1<<<nscan, 256, 0, stream>>>(CNT, OFF, BS, N);
  k_scan2<<<1, 64, 0, stream>>>(BS, BOF, nscan);
  k_scan3<<<nscan, 256, 0, stream>>>(OFF, BOF, N);
  k_fill <<<(E + 255)/256, 256, 0, stream>>>(dstv, OFF, FIL, EID, E);

  // ---- input projection + BN + relu -> L0 ----
  k_inproj<<<(N + 127)/128, 256, 0, stream>>>(x, W_in, b_in, L0, STD_BN(STD,0), N);
  k_bnfin<<<1, 128, 0, stream>>>(STD_BN(STD,0), g_in, beta_in, STF + 0, 0, invN);
  {
    long t4 = (long)N*32;
    k_affrelu<<<(unsigned)((t4 + 255)/256), 256, 0, stream>>>(L0, STF + 0, t4);
  }

  // ---- GINE aggregation (CSR gather) ----
  k_gine_gather<<<(N + 3)/4, 256, 0, stream>>>(OFF, EID, srcv, eattr, We, be, L0, AG, N);

  // ---- GINE MLP (MFMA split-f16, no-LDS) ----
  k_mfma<0,0,128,256><<<nb, 256, 0, stream>>>(L0, AG, STF, 0, BP1, b1, nullptr, nullptr, X2, N);
  k_colstats<256><<<nb, 256, 0, stream>>>(X2, STD_BN(STD,1), N);
  k_bnfin<<<1, 256, 0, stream>>>(STD_BN(STD,1), g1, beta1, STF + 512, 0, invN);
  k_mfma<1,1,256,128><<<nb, 256, 0, stream>>>(X2, nullptr, STF, 512, BP2, b2, L0, skip0, P1, N);
  k_colstats<128><<<nb, 256, 0, stream>>>(P1, STD_BN(STD,2), N);
  k_bnfin<<<1, 128, 0, stream>>>(STD_BN(STD,2), g_n0, b_n0, STF + 1024, 0, invN);

  // ---- GAT head-by-head: MFMA transform (xl|xr) + fused attention ----
  for (int h = 0; h < 4; ++h) {
    k_mfma<2,0,128,256><<<nb, 256, 0, stream>>>(P1, nullptr, STF, 1024,
                                                BPG + (size_t)h*8192, BPB + h*256,
                                                nullptr, nullptr, X2, N);
    k_gat_attn<<<(N + 3)/4, 256, 0, stream>>>(OFF, EID, srcv, eattr, X2, Weg, att,
                                              AG, N, h, (h == 0) ? 1 : 0);
  }

  // ---- post + BN n1 + final ----
  k_gat_post<<<(N + 255)/256, 128, 0, stream>>>(AG, P1, STF, bias_g, skip1, STD_BN(STD,3), N);
  k_bnfin<<<1, 128, 0, stream>>>(STD_BN(STD,3), g_n1, b_n1, STF + 1536, 0, invN);
  {
    long t4 = (long)N*32;
    k_final<<<(unsigned)((t4 + 255)/256), 256, 0, stream>>>(L0, P1, AG, STF, t4);
  }
  (void)n_in; (void)out_size; (void)ws_size;
}